// Round 9
// baseline (183.177 us; speedup 1.0000x reference)
//
#include <hip/hip_runtime.h>

typedef unsigned short u16;
typedef unsigned int u32;
typedef __attribute__((ext_vector_type(8))) short short8;
typedef __attribute__((ext_vector_type(4))) float f32x4;

#define NATOMS 8000
#define MNBR 12
#define EPSV 1e-5f
#define AB 4
#define ROWS 48
#define NBLK 2000
#define K2REC 1664

// u/v LDS buffer geometry (12 groups of 4 rows; group = 4*256B + 32B pad)
#define STG_B 12672
__device__ __forceinline__ int stg_idx(int row, int col) {  // u16 index
  return (row >> 2) * 528 + (row & 3) * 128 + col;
}

// ---- ws layout (bytes) ----
#define XB_OFF 0                 // u16 XB[8000][64] bf16 (1 MB, L2-resident)
#define WTA_OFF 1024000          // u16 WtAtom[768][64]
#define WTE_OFF 1122304          // u16 WtEdge[512][64]
#define WAT_OFF 1187840          // f32 WaT[128][64] (W_3body Wa transposed)
#define SSUM_OFF 1220608         // f32 ssum[1664] + bn2sum[128]
#define PARAMS_OFF 1227776       // f32 params[768]
#define TBUF_OFF 1230848         // f32 tbuf[8000*64]
#define WS_NEED 3278848

// ssum layout (f32 indices)
#define SS_BN1S 0
#define SS_BN1S2 128
#define SS_BNES 256
#define SS_BNES2 384
#define SS_U2 512
#define SS_V2 640
#define SS_A 768
#define SS_A2 896
#define SS_UB 1024
#define SS_VB 1152
#define SS_AU 1280
#define SS_AV 1408
#define SS_UV 1536

__device__ __forceinline__ u16 f2bf(float f) {
  u32 u = __float_as_uint(f);
  u += 0x7FFFu + ((u >> 16) & 1u);
  return (u16)(u >> 16);
}
__device__ __forceinline__ float bf2f(u16 h) { return __uint_as_float(((u32)h) << 16); }

__device__ __forceinline__ float sigf(float x) {
  return __builtin_amdgcn_rcpf(1.f + __expf(-x));
}
__device__ __forceinline__ float spf(float x) {
  return fmaxf(x, 0.f) + __logf(1.f + __expf(-fabsf(x)));
}

__device__ __forceinline__ void mfma16(f32x4 &acc, short8 a, short8 b) {
  asm volatile("v_mfma_f32_16x16x32_bf16 %0, %1, %2, %0" : "+v"(acc) : "v"(a), "v"(b));
}
__device__ __forceinline__ void accfence(f32x4 &a) {
  asm volatile("s_nop 7\ns_nop 7\ns_nop 7" : "+v"(a));
}
__device__ __forceinline__ void initfence(f32x4 &a) {
  asm volatile("s_nop 1" : "+v"(a));
}

// stage 16 f32 -> 16 bf16 into XOR-swizzled LDS row (row stride 128B)
__device__ __forceinline__ void stage_row16(short* lds, int row, int c16, const float* __restrict__ src) {
  const float4* s4 = reinterpret_cast<const float4*>(src);
  float4 q0 = s4[0], q1 = s4[1], q2 = s4[2], q3 = s4[3];
  short8 lo, hi;
  lo[0]=(short)f2bf(q0.x); lo[1]=(short)f2bf(q0.y); lo[2]=(short)f2bf(q0.z); lo[3]=(short)f2bf(q0.w);
  lo[4]=(short)f2bf(q1.x); lo[5]=(short)f2bf(q1.y); lo[6]=(short)f2bf(q1.z); lo[7]=(short)f2bf(q1.w);
  hi[0]=(short)f2bf(q2.x); hi[1]=(short)f2bf(q2.y); hi[2]=(short)f2bf(q2.z); hi[3]=(short)f2bf(q2.w);
  hi[4]=(short)f2bf(q3.x); hi[5]=(short)f2bf(q3.y); hi[6]=(short)f2bf(q3.z); hi[7]=(short)f2bf(q3.w);
  int base = row * 128 + c16 * 2;
  int sw = (row & 7) << 4;
  *reinterpret_cast<short8*>(reinterpret_cast<char*>(lds) + (base ^ sw)) = lo;
  *reinterpret_cast<short8*>(reinterpret_cast<char*>(lds) + ((base + 16) ^ sw)) = hi;
}

// stage x_j (48 edges) + x_own (4) bf16 rows from XB into swizzled xjT[64][64]
__device__ __forceinline__ void stage_xj(const u16* __restrict__ XB, const int* __restrict__ nidx,
                                         int eb, int ab, char* xjT, int t) {
  for (int s = t; s < 512; s += 256) {
    int r = s >> 3, j = s & 7;
    uint4 val = make_uint4(0u, 0u, 0u, 0u);
    if (r < 48) {
      int idx = nidx[eb + r];
      val = *reinterpret_cast<const uint4*>(XB + (size_t)idx * 64 + j * 8);
    } else if (r < 52) {
      val = *reinterpret_cast<const uint4*>(XB + (size_t)(ab + r - 48) * 64 + j * 8);
    }
    int off = (r * 128 + j * 16) ^ ((r & 7) << 4);
    *reinterpret_cast<uint4*>(xjT + off) = val;
  }
}

__device__ __forceinline__ short8 lds_afrag(const short* lds, int row, int kbyte) {
  int off = (row * 128 + kbyte) ^ ((row & 7) << 4);
  return *reinterpret_cast<const short8*>(reinterpret_cast<const char*>(lds) + off);
}

// acc = xj@WTA[baseA..] + nbr@WTE[baseE..]  (48 rows x 128 cols, K=64)
template <int RT>
__device__ __forceinline__ void mfma_dual(const short* xjT, const short* nbrT,
                                          const u16* __restrict__ WTA, const u16* __restrict__ WTE,
                                          int baseA, int baseE, int w, int l,
                                          f32x4 (&acc)[RT][2]) {
  short8 ba[2][2], be[2][2];
#pragma unroll
  for (int p = 0; p < 2; ++p) {
    int colg = ((w + p * 4) << 4) + (l & 15);
#pragma unroll
    for (int kc = 0; kc < 2; ++kc) {
      ba[p][kc] = *reinterpret_cast<const short8*>(WTA + (size_t)(baseA + colg) * 64 + kc * 32 + ((l >> 4) << 3));
      be[p][kc] = *reinterpret_cast<const short8*>(WTE + (size_t)(baseE + colg) * 64 + kc * 32 + ((l >> 4) << 3));
    }
  }
#pragma unroll
  for (int rt = 0; rt < RT; ++rt)
#pragma unroll
    for (int p = 0; p < 2; ++p) { acc[rt][p] = f32x4{0.f, 0.f, 0.f, 0.f}; initfence(acc[rt][p]); }
#pragma unroll
  for (int rt = 0; rt < RT; ++rt) {
    int arow = rt * 16 + (l & 15);
    short8 x0 = lds_afrag(xjT, arow, (l >> 4) << 4);
    short8 x1 = lds_afrag(xjT, arow, 64 + ((l >> 4) << 4));
    short8 n0 = lds_afrag(nbrT, arow, (l >> 4) << 4);
    short8 n1 = lds_afrag(nbrT, arow, 64 + ((l >> 4) << 4));
#pragma unroll
    for (int p = 0; p < 2; ++p) {
      mfma16(acc[rt][p], x0, ba[p][0]);
      mfma16(acc[rt][p], x1, ba[p][1]);
      mfma16(acc[rt][p], n0, be[p][0]);
      mfma16(acc[rt][p], n1, be[p][1]);
    }
  }
#pragma unroll
  for (int rt = 0; rt < RT; ++rt)
#pragma unroll
    for (int p = 0; p < 2; ++p) accfence(acc[rt][p]);
}

// own projection: xjT rows 48-51 @ WTA[baseO..] -> ownv[4][128] f32 (per-wave cols)
__device__ __forceinline__ void mfma_own(const short* xjT, const u16* __restrict__ WTA,
                                         int baseO, int w, int l, float* ownv) {
  short8 bo[2][2];
#pragma unroll
  for (int p = 0; p < 2; ++p) {
    int colg = ((w + p * 4) << 4) + (l & 15);
#pragma unroll
    for (int kc = 0; kc < 2; ++kc)
      bo[p][kc] = *reinterpret_cast<const short8*>(WTA + (size_t)(baseO + colg) * 64 + kc * 32 + ((l >> 4) << 3));
  }
  int arow = 48 + (l & 15);
  short8 x0 = lds_afrag(xjT, arow, (l >> 4) << 4);
  short8 x1 = lds_afrag(xjT, arow, 64 + ((l >> 4) << 4));
  f32x4 acc[2];
#pragma unroll
  for (int p = 0; p < 2; ++p) {
    acc[p] = f32x4{0.f, 0.f, 0.f, 0.f};
    initfence(acc[p]);
    mfma16(acc[p], x0, bo[p][0]);
    mfma16(acc[p], x1, bo[p][1]);
  }
#pragma unroll
  for (int p = 0; p < 2; ++p) accfence(acc[p]);
  if (l < 16) {
    int col0 = (w << 4) + l;
#pragma unroll
    for (int r = 0; r < 4; ++r) {
      ownv[r * 128 + col0] = acc[0][r];
      ownv[r * 128 + col0 + 64] = acc[1][r];
    }
  }
}

// f32 a-term dot: dv[2] = xown[2h,2h+1] . WaT[c]
__device__ __forceinline__ void aterm_dot(const float* __restrict__ WaT, const float* xown,
                                          int c, int h, float& dv0, float& dv1) {
  const float4* wa4 = reinterpret_cast<const float4*>(WaT + (size_t)c * 64);
  const float4* x0 = reinterpret_cast<const float4*>(xown + (2 * h) * 64);
  const float4* x1 = reinterpret_cast<const float4*>(xown + (2 * h + 1) * 64);
  dv0 = 0.f; dv1 = 0.f;
#pragma unroll
  for (int q = 0; q < 16; ++q) {
    float4 wv = wa4[q], a4 = x0[q], b4 = x1[q];
    dv0 += a4.x * wv.x + a4.y * wv.y + a4.z * wv.z + a4.w * wv.w;
    dv1 += b4.x * wv.x + b4.y * wv.y + b4.z * wv.z + b4.w * wv.w;
  }
}

// ---------------- K0: XB + weight transposes + WaT + zero ssum ----------------
__global__ __launch_bounds__(256) void k0_prep(const float* __restrict__ atom_in,
                                               const float* __restrict__ W_full,
                                               const float* __restrict__ W_edge,
                                               const float* __restrict__ W_3body,
                                               u16* __restrict__ XB,
                                               u16* __restrict__ WTA, u16* __restrict__ WTE,
                                               float* __restrict__ WaT,
                                               float* __restrict__ ssum) {
  int t = blockIdx.x * 256 + threadIdx.x;
  if (t < 1792) ssum[t] = 0.f;
  if (t < 8192) { int c = t >> 6, k = t & 63; WaT[t] = W_3body[k * 128 + c]; }
  if (t < 49152) {  // WtAtom: 768 cols x 64 k
    int col = t >> 6, k = t & 63;
    int blk = col >> 7, c = col & 127;
    float v;
    switch (blk) {
      case 0: v = W_full[k * 128 + c]; break;          // W1 (x_i)
      case 1: v = W_full[(64 + k) * 128 + c]; break;   // W2 (x_j)
      case 2: v = W_edge[k * 128 + c]; break;          // We1
      case 3: v = W_edge[(64 + k) * 128 + c]; break;   // We2
      case 4: v = W_3body[(64 + k) * 128 + c]; break;  // Wj
      default: v = W_3body[(128 + k) * 128 + c]; break;// Wl
    }
    WTA[t] = f2bf(v);
  } else if (t < 81920) {  // WtEdge: 512 cols x 64 k
    int u = t - 49152;
    int col = u >> 6, k = u & 63;
    int blk = col >> 7, c = col & 127;
    float v;
    switch (blk) {
      case 0: v = W_full[(128 + k) * 128 + c]; break;   // W3
      case 1: v = W_edge[(128 + k) * 128 + c]; break;   // We3
      case 2: v = W_3body[(192 + k) * 128 + c]; break;  // Wij
      default: v = W_3body[(256 + k) * 128 + c]; break; // Wil
    }
    WTE[u] = f2bf(v);
  }
  if (t < NATOMS * 64) XB[t] = f2bf(atom_in[t]);
}

// ---------------- K2a: bn1/bne partials (b = 0,1) ----------------
__global__ __launch_bounds__(256, 4) void k2a_stats(const float* __restrict__ nbr_fea,
                                                    const int* __restrict__ nidx,
                                                    const float* __restrict__ b_full,
                                                    const float* __restrict__ b_edge,
                                                    const u16* __restrict__ XB,
                                                    const u16* __restrict__ WTA,
                                                    const u16* __restrict__ WTE,
                                                    float* __restrict__ k2scr) {
  __shared__ __align__(16) char smem[16384];
  short* nbrT = (short*)smem;                 // 6144
  char* xjT   = smem + 6144;                  // 8192
  float* ownv = (float*)(smem + 14336);       // 2048
  int t = threadIdx.x, l = t & 63, w = t >> 6;
  int ab = blockIdx.x * AB, eb = ab * 12;
  float* sc = k2scr + (size_t)blockIdx.x * K2REC;

  for (int u = t; u < ROWS * 4; u += 256) {
    int row = u >> 2, c16 = (u & 3) * 16;
    stage_row16(nbrT, row, c16, nbr_fea + (size_t)(eb + row) * 64 + c16);
  }
  stage_xj(XB, nidx, eb, ab, xjT, t);
  __syncthreads();

#pragma unroll
  for (int b = 0; b < 2; ++b) {
    f32x4 acc[3][2];
    mfma_dual<3>((short*)xjT, nbrT, WTA, WTE, b ? 384 : 128, b * 128, w, l, acc);
    mfma_own((short*)xjT, WTA, b ? 256 : 0, w, l, ownv);
    int col0 = (w << 4) + (l & 15), col1 = col0 + 64;
    int g = l >> 4;
    const float* bp = b ? b_edge : b_full;
    float bias0 = bp[col0], bias1 = bp[col1];
    float vs0 = 0.f, vs1 = 0.f, q0 = 0.f, q1 = 0.f;
#pragma unroll
    for (int rt = 0; rt < 3; ++rt) {
      int a12 = (rt * 16 + g * 4) / 12;
      float o0 = ownv[a12 * 128 + col0] + bias0;
      float o1 = ownv[a12 * 128 + col1] + bias1;
#pragma unroll
      for (int r = 0; r < 4; ++r) {
        float v0 = acc[rt][0][r] + o0;
        float v1 = acc[rt][1][r] + o1;
        vs0 += v0; q0 += v0 * v0; vs1 += v1; q1 += v1 * v1;
      }
    }
    vs0 += __shfl_xor(vs0, 16); vs0 += __shfl_xor(vs0, 32);
    vs1 += __shfl_xor(vs1, 16); vs1 += __shfl_xor(vs1, 32);
    q0 += __shfl_xor(q0, 16); q0 += __shfl_xor(q0, 32);
    q1 += __shfl_xor(q1, 16); q1 += __shfl_xor(q1, 32);
    if (l < 16) {
      int base = b ? 256 : 0;
      sc[base + col0] = vs0;
      sc[base + 128 + col0] = q0;
      sc[base + col1] = vs1;
      sc[base + 128 + col1] = q1;
    }
  }
}

// ---------------- K2b: u/v sq partials (b = 2,3) + analytic bn3 partials ----------------
__global__ __launch_bounds__(256, 4) void k2b_stats(const float* __restrict__ atom_in,
                                                    const float* __restrict__ nbr_fea,
                                                    const int* __restrict__ nidx,
                                                    const float* __restrict__ WaT,
                                                    const float* __restrict__ b_3body,
                                                    const u16* __restrict__ XB,
                                                    const u16* __restrict__ WTA,
                                                    const u16* __restrict__ WTE,
                                                    float* __restrict__ k2scr) {
  __shared__ __align__(16) char smem[23040];
  short* nbrT   = (short*)smem;                 // 6144
  char* xjT     = smem + 6144;                  // 8192
  float* ubar   = (float*)(smem + 14336);       // 2048
  float* vbar   = (float*)(smem + 16384);       // 2048
  float* xown   = (float*)(smem + 18432);       // 1024
  float* redscr = (float*)(smem + 19456);       // 3584
  int t = threadIdx.x, l = t & 63, w = t >> 6;
  int ab = blockIdx.x * AB, eb = ab * 12;
  float* sc = k2scr + (size_t)blockIdx.x * K2REC;

  for (int u = t; u < ROWS * 4; u += 256) {
    int row = u >> 2, c16 = (u & 3) * 16;
    stage_row16(nbrT, row, c16, nbr_fea + (size_t)(eb + row) * 64 + c16);
  }
  stage_xj(XB, nidx, eb, ab, xjT, t);
  ubar[t] = 0.f; ubar[256 + t] = 0.f; vbar[t] = 0.f; vbar[256 + t] = 0.f;
  xown[t] = atom_in[(size_t)ab * 64 + t];
  __syncthreads();

#pragma unroll
  for (int b = 2; b < 4; ++b) {
    f32x4 acc[3][2];
    mfma_dual<3>((short*)xjT, nbrT, WTA, WTE, (b == 2) ? 512 : 640, b * 128, w, l, acc);
    float* uvb = (b == 2) ? ubar : vbar;
    int col0 = (w << 4) + (l & 15), col1 = col0 + 64;
    int g = l >> 4;
    float q0 = 0.f, q1 = 0.f;
#pragma unroll
    for (int rt = 0; rt < 3; ++rt) {
      int a12 = (rt * 16 + g * 4) / 12;
      float s0 = 0.f, s1 = 0.f;
#pragma unroll
      for (int r = 0; r < 4; ++r) {
        float v0 = acc[rt][0][r];
        float v1 = acc[rt][1][r];
        s0 += v0; q0 += v0 * v0; s1 += v1; q1 += v1 * v1;
      }
      atomicAdd(&uvb[a12 * 128 + col0], s0);
      atomicAdd(&uvb[a12 * 128 + col1], s1);
    }
    q0 += __shfl_xor(q0, 16); q0 += __shfl_xor(q0, 32);
    q1 += __shfl_xor(q1, 16); q1 += __shfl_xor(q1, 32);
    if (l < 16) {
      int base = (b == 2) ? SS_U2 : SS_V2;
      sc[base + col0] = q0;
      sc[base + col1] = q1;
    }
  }
  __syncthreads();

  // analytic bn3 partials
  {
    int c = t & 127, h = t >> 7;
    float dv0, dv1;
    aterm_dot(WaT, xown, c, h, dv0, dv1);
    float b3v = b_3body[c];
    float pA = 0.f, pA2 = 0.f, pUb = 0.f, pVb = 0.f, pAU = 0.f, pAV = 0.f, pUV = 0.f;
#pragma unroll
    for (int aa = 0; aa < 2; ++aa) {
      int a = 2 * h + aa;
      float aval = (aa ? dv1 : dv0) + b3v;
      float ub = ubar[a * 128 + c] * (1.f / 12.f);
      float vb = vbar[a * 128 + c] * (1.f / 12.f);
      pA += aval; pA2 += aval * aval; pUb += ub; pVb += vb;
      pAU += aval * ub; pAV += aval * vb; pUV += ub * vb;
    }
    if (h == 1) {
      float* rs = &redscr[c * 7];
      rs[0] = pA; rs[1] = pA2; rs[2] = pUb; rs[3] = pVb; rs[4] = pAU; rs[5] = pAV; rs[6] = pUV;
    }
    __syncthreads();
    if (h == 0) {
      const float* rs = &redscr[c * 7];
      sc[SS_A + c] = pA + rs[0];
      sc[SS_A2 + c] = pA2 + rs[1];
      sc[SS_UB + c] = pUb + rs[2];
      sc[SS_VB + c] = pVb + rs[3];
      sc[SS_AU + c] = pAU + rs[4];
      sc[SS_AV + c] = pAV + rs[5];
      sc[SS_UV + c] = pUV + rs[6];
    }
  }
}

// ---------------- K3r: reduce k2 scratch -> ssum ----------------
__global__ __launch_bounds__(256) void k3r_reduce(const float* __restrict__ k2scr,
                                                  float* __restrict__ ssum) {
  int cb = blockIdx.x & 1, ch = blockIdx.x >> 1;
  int f = cb * 256 + threadIdx.x;
  if (f >= K2REC / 4) return;
  int r0 = ch * 32;
  if (r0 >= NBLK) return;
  int r1 = min(r0 + 32, NBLK);
  float s0 = 0.f, s1 = 0.f, s2 = 0.f, s3 = 0.f;
#pragma unroll 8
  for (int r = r0; r < r1; ++r) {
    float4 v = *reinterpret_cast<const float4*>(k2scr + (size_t)r * K2REC + f * 4);
    s0 += v.x; s1 += v.y; s2 += v.z; s3 += v.w;
  }
  atomicAdd(&ssum[f * 4 + 0], s0);
  atomicAdd(&ssum[f * 4 + 1], s1);
  atomicAdd(&ssum[f * 4 + 2], s2);
  atomicAdd(&ssum[f * 4 + 3], s3);
}

// ---------------- K3p: finalize bn1/bne/bn3 affine params ----------------
__global__ void k3p_params(const float* __restrict__ ssum,
                           const float* __restrict__ g1, const float* __restrict__ be1,
                           const float* __restrict__ ge, const float* __restrict__ bee,
                           const float* __restrict__ g3, const float* __restrict__ be3,
                           float* __restrict__ params) {
  int c = threadIdx.x;
  if (c >= 128) return;
  const float cnt1 = 1.f / 96000.f;
  {
    float m = ssum[SS_BN1S + c] * cnt1;
    float var = ssum[SS_BN1S2 + c] * cnt1 - m * m;
    float s = g1[c] * rsqrtf(fmaxf(var, 0.f) + EPSV);
    params[c] = s; params[128 + c] = be1[c] - m * s;
  }
  {
    float m = ssum[SS_BNES + c] * cnt1;
    float var = ssum[SS_BNES2 + c] * cnt1 - m * m;
    float s = ge[c] * rsqrtf(fmaxf(var, 0.f) + EPSV);
    params[256 + c] = s; params[384 + c] = bee[c] - m * s;
  }
  {
    float Nf = (float)NATOMS;
    float A_ = ssum[SS_A + c], A2 = ssum[SS_A2 + c];
    float U2 = ssum[SS_U2 + c], V2 = ssum[SS_V2 + c];
    float Ub = ssum[SS_UB + c], Vb = ssum[SS_VB + c];
    float AU = ssum[SS_AU + c], AV = ssum[SS_AV + c], UV = ssum[SS_UV + c];
    float m = (A_ + Ub + Vb) / Nf;
    float ez2 = A2 / Nf + (U2 + V2) / (Nf * 12.f) + 2.f * (AU + AV + UV) / Nf;
    float var = ez2 - m * m;
    float s = g3[c] * rsqrtf(fmaxf(var, 0.f) + EPSV);
    params[512 + c] = s; params[640 + c] = be3[c] - m * s;
  }
}

// ---------------- K4a: gates (b = 0,1) -> tbuf + out_nbr ----------------
__global__ __launch_bounds__(256, 4) void k4a_main(const float* __restrict__ nbr_fea,
                                                   const int* __restrict__ nidx,
                                                   const float* __restrict__ b_full,
                                                   const float* __restrict__ b_edge,
                                                   const u16* __restrict__ XB,
                                                   const u16* __restrict__ WTA,
                                                   const u16* __restrict__ WTE,
                                                   const float* __restrict__ params,
                                                   float* __restrict__ tbuf,
                                                   float* __restrict__ out_nbr) {
  __shared__ __align__(16) char smem[19456];
  short* nbrT     = (short*)smem;                 // 6144
  char* xjT       = smem + 6144;                  // 8192
  float* ownv     = (float*)(smem + 14336);       // 2048
  float* t2buf    = (float*)(smem + 16384);       // 1024
  float* params_s = (float*)(smem + 17408);       // 2048
  int t = threadIdx.x, l = t & 63, w = t >> 6;
  int ab = blockIdx.x * AB, eb = ab * 12;

  for (int u = t; u < ROWS * 4; u += 256) {
    int row = u >> 2, c16 = (u & 3) * 16;
    stage_row16(nbrT, row, c16, nbr_fea + (size_t)(eb + row) * 64 + c16);
  }
  stage_xj(XB, nidx, eb, ab, xjT, t);
  params_s[t] = params[t];
  params_s[t + 256] = params[t + 256];
  t2buf[t] = 0.f;
  __syncthreads();

#pragma unroll
  for (int b = 0; b < 2; ++b) {
    f32x4 acc[3][2];
    mfma_dual<3>((short*)xjT, nbrT, WTA, WTE, b ? 384 : 128, b * 128, w, l, acc);
    mfma_own((short*)xjT, WTA, b ? 256 : 0, w, l, ownv);
    int col0 = (w << 4) + (l & 15), col1 = col0 + 64;
    int g = l >> 4;
    const float* bp = b ? b_edge : b_full;
    float bias0 = bp[col0], bias1 = bp[col1];
    float sc0 = params_s[b * 256 + col0], sh0 = params_s[b * 256 + 128 + col0];
    float sc1 = params_s[b * 256 + col1], sh1 = params_s[b * 256 + 128 + col1];
#pragma unroll
    for (int rt = 0; rt < 3; ++rt) {
      int a12 = (rt * 16 + g * 4) / 12;
      float o0 = ownv[a12 * 128 + col0] + bias0;
      float o1 = ownv[a12 * 128 + col1] + bias1;
      float gsum = 0.f;
#pragma unroll
      for (int r = 0; r < 4; ++r) {
        int row = rt * 16 + g * 4 + r;
        float v0 = acc[rt][0][r] + o0;
        float v1 = acc[rt][1][r] + o1;
        float gate = sigf(v0 * sc0 + sh0) * spf(v1 * sc1 + sh1);
        if (b == 0) {
          gsum += gate;
        } else {
          size_t eg = (size_t)(eb + row) * 64 + col0;
          out_nbr[eg] = nbr_fea[eg] + gate;
        }
      }
      if (b == 0) atomicAdd(&t2buf[a12 * 64 + col0], gsum);
    }
  }
  __syncthreads();
  tbuf[(size_t)(ab + w) * 64 + l] = t2buf[t];
}

// ---------------- K4b: 3-body (b = 2,3) + bn2 partials ----------------
__global__ __launch_bounds__(256, 4) void k4b_main(const float* __restrict__ atom_in,
                                                   const float* __restrict__ nbr_fea,
                                                   const int* __restrict__ nidx,
                                                   const float* __restrict__ WaT,
                                                   const float* __restrict__ b_3body,
                                                   const u16* __restrict__ XB,
                                                   const u16* __restrict__ WTA,
                                                   const u16* __restrict__ WTE,
                                                   const float* __restrict__ params,
                                                   float* __restrict__ tbuf,
                                                   float* __restrict__ bn2scr) {
  __shared__ __align__(16) char smem[31104];
  short* nbrT    = (short*)smem;                 // 6144
  char* xjT      = smem + 6144;                  // 8192
  u16* u_s       = (u16*)(smem + 14336);         // 12672
  float* a_s     = (float*)(smem + 27008);       // 2048
  float* xown    = (float*)(smem + 29056);       // 1024
  float* p3_s    = (float*)(smem + 30080);       // 1024
  u16* v_s       = (u16*)smem;                   // alias nbrT+xjT (post b=3 MFMA)
  float* redscr2 = (float*)(smem + 14336);       // alias u_s (post 3-body)
  int t = threadIdx.x, l = t & 63, w = t >> 6;
  int ab = blockIdx.x * AB, eb = ab * 12;

  for (int u = t; u < ROWS * 4; u += 256) {
    int row = u >> 2, c16 = (u & 3) * 16;
    stage_row16(nbrT, row, c16, nbr_fea + (size_t)(eb + row) * 64 + c16);
  }
  stage_xj(XB, nidx, eb, ab, xjT, t);
  xown[t] = atom_in[(size_t)ab * 64 + t];
  p3_s[t] = params[512 + t];
  float two_body = tbuf[(size_t)(ab + w) * 64 + l];
  __syncthreads();

  // a' = (x_i @ Wa + b3) * s3 + t3 (f32)
  {
    int c = t & 127, h = t >> 7;
    float dv0, dv1;
    aterm_dot(WaT, xown, c, h, dv0, dv1);
    float s3 = p3_s[c], t3 = p3_s[128 + c];
    float b3v = b_3body[c];
    a_s[(2 * h) * 128 + c] = (dv0 + b3v) * s3 + t3;
    a_s[(2 * h + 1) * 128 + c] = (dv1 + b3v) * s3 + t3;
  }

  // phase b=2 -> u_s
  {
    f32x4 acc[3][2];
    mfma_dual<3>((short*)xjT, nbrT, WTA, WTE, 512, 256, w, l, acc);
    int col0 = (w << 4) + (l & 15), col1 = col0 + 64;
    int g = l >> 4;
    float s30 = p3_s[col0], s31 = p3_s[col1];
#pragma unroll
    for (int rt = 0; rt < 3; ++rt) {
#pragma unroll
      for (int r = 0; r < 4; ++r) {
        int row = rt * 16 + g * 4 + r;
        u_s[stg_idx(row, col0)] = f2bf(acc[rt][0][r] * s30);
        u_s[stg_idx(row, col1)] = f2bf(acc[rt][1][r] * s31);
      }
    }
  }
  // phase b=3 -> v_s (aliases nbrT/xjT; barrier after MFMA reads)
  {
    f32x4 acc[3][2];
    mfma_dual<3>((short*)xjT, nbrT, WTA, WTE, 640, 384, w, l, acc);
    __syncthreads();  // all waves done reading nbrT/xjT
    int col0 = (w << 4) + (l & 15), col1 = col0 + 64;
    int g = l >> 4;
    float s30 = p3_s[col0], s31 = p3_s[col1];
#pragma unroll
    for (int rt = 0; rt < 3; ++rt) {
#pragma unroll
      for (int r = 0; r < 4; ++r) {
        int row = rt * 16 + g * 4 + r;
        v_s[stg_idx(row, col0)] = f2bf(acc[rt][0][r] * s30);
        v_s[stg_idx(row, col1)] = f2bf(acc[rt][1][r] * s31);
      }
    }
  }
  __syncthreads();

  // 3-body via exp factorization: sig(a+u+v) = rcp(1+E*F), sp = ln2*log2(1+G*H)
  float acc3 = 0.f;
  {
    int c = l, a = w;
    float af = a_s[a * 128 + c], ac = a_s[a * 128 + 64 + c];
    float Fl[12], Hl[12];
#pragma unroll
    for (int j2 = 0; j2 < 12; ++j2) {
      float vf = bf2f(v_s[stg_idx(a * 12 + j2, c)]);
      float vc = bf2f(v_s[stg_idx(a * 12 + j2, 64 + c)]);
      Fl[j2] = __expf(-vf);
      Hl[j2] = __expf(vc);
    }
    for (int j = 0; j < 12; ++j) {
      float uf = bf2f(u_s[stg_idx(a * 12 + j, c)]);
      float uc = bf2f(u_s[stg_idx(a * 12 + j, 64 + c)]);
      float Ej = __expf(-(af + uf));
      float Gj = __expf(ac + uc);
#pragma unroll
      for (int l2 = 0; l2 < 12; ++l2) {
        float p = fmaf(Ej, Fl[l2], 1.f);
        float q = fmaf(Gj, Hl[l2], 1.f);
        acc3 += __builtin_amdgcn_rcpf(p) * __log2f(q);
      }
    }
  }
  __syncthreads();

  // t = two + three body; bn2 partials (column-major scratch)
  {
    float x = two_body + acc3 * 0.6931471805599453f;
    tbuf[(size_t)(ab + w) * 64 + l] = x;
    redscr2[t] = x;
    redscr2[256 + t] = x * x;
    __syncthreads();
    if (t < 64) {
      float s = redscr2[t] + redscr2[t + 64] + redscr2[t + 128] + redscr2[t + 192];
      float s2 = redscr2[256 + t] + redscr2[256 + t + 64] + redscr2[256 + t + 128] + redscr2[256 + t + 192];
      bn2scr[(size_t)t * 2048 + blockIdx.x] = s;
      bn2scr[(size_t)(64 + t) * 2048 + blockIdx.x] = s2;
    }
  }
}

// ---------------- K5: reduce bn2 partials -> bn2sum[128] ----------------
__global__ __launch_bounds__(256) void k5_reduce(const float* __restrict__ bn2scr,
                                                 float* __restrict__ bn2sum) {
  __shared__ float wsum[4];
  int c = blockIdx.x, t = threadIdx.x;
  float s = 0.f;
#pragma unroll 4
  for (int i = t; i < NBLK; i += 256) s += bn2scr[(size_t)c * 2048 + i];
  s += __shfl_xor(s, 1); s += __shfl_xor(s, 2); s += __shfl_xor(s, 4);
  s += __shfl_xor(s, 8); s += __shfl_xor(s, 16); s += __shfl_xor(s, 32);
  if ((t & 63) == 0) wsum[t >> 6] = s;
  __syncthreads();
  if (t == 0) bn2sum[c] = wsum[0] + wsum[1] + wsum[2] + wsum[3];
}

// ---------------- K6: bn2 + final softplus ----------------
__global__ __launch_bounds__(256) void k6_out(const float* __restrict__ atom_in,
                                              const float* __restrict__ tbuf,
                                              const float* __restrict__ bn2sum,
                                              const float* __restrict__ g2,
                                              const float* __restrict__ be2,
                                              float* __restrict__ out_atom) {
  __shared__ float sc[64], sh[64];
  int t = threadIdx.x;
  if (t < 64) {
    float S = bn2sum[t], S2 = bn2sum[64 + t];
    float m = S * (1.f / (float)NATOMS);
    float var = S2 * (1.f / (float)NATOMS) - m * m;
    float s = g2[t] * rsqrtf(fmaxf(var, 0.f) + EPSV);
    sc[t] = s; sh[t] = be2[t] - m * s;
  }
  __syncthreads();
  int i = blockIdx.x * 256 + t;
  if (i < NATOMS * 64) {
    int c = i & 63;
    float v = atom_in[i] + tbuf[i] * sc[c] + sh[c];
    out_atom[i] = spf(v);
  }
}

extern "C" void kernel_launch(void* const* d_in, const int* in_sizes, int n_in,
                              void* d_out, int out_size, void* d_ws, size_t ws_size,
                              hipStream_t stream) {
  if (ws_size < (size_t)WS_NEED) return;
  const float* atom_in = (const float*)d_in[0];
  const float* nbr_fea = (const float*)d_in[1];
  const int* nidx = (const int*)d_in[2];
  const float* W_full = (const float*)d_in[3];
  const float* b_full = (const float*)d_in[4];
  const float* g1 = (const float*)d_in[5];
  const float* be1 = (const float*)d_in[6];
  const float* W_edge = (const float*)d_in[7];
  const float* b_edge = (const float*)d_in[8];
  const float* ge = (const float*)d_in[9];
  const float* bee = (const float*)d_in[10];
  const float* W_3body = (const float*)d_in[11];
  const float* b_3body = (const float*)d_in[12];
  const float* g3 = (const float*)d_in[13];
  const float* be3 = (const float*)d_in[14];
  const float* g2 = (const float*)d_in[15];
  const float* be2 = (const float*)d_in[16];

  char* ws = (char*)d_ws;
  u16* XB = (u16*)(ws + XB_OFF);
  u16* WTA = (u16*)(ws + WTA_OFF);
  u16* WTE = (u16*)(ws + WTE_OFF);
  float* WaT = (float*)(ws + WAT_OFF);
  float* ssum = (float*)(ws + SSUM_OFF);
  float* bn2sum = ssum + K2REC;
  float* params = (float*)(ws + PARAMS_OFF);
  float* tbuf = (float*)(ws + TBUF_OFF);

  float* out_atom = (float*)d_out;
  float* out_nbr = out_atom + NATOMS * 64;
  float* k2scr = out_nbr;    // scratch until k4a overwrites
  float* bn2scr = out_atom;  // scratch until k6 overwrites

  k0_prep<<<2000, 256, 0, stream>>>(atom_in, W_full, W_edge, W_3body, XB, WTA, WTE, WaT, ssum);
  k2a_stats<<<NBLK, 256, 0, stream>>>(nbr_fea, nidx, b_full, b_edge, XB, WTA, WTE, k2scr);
  k2b_stats<<<NBLK, 256, 0, stream>>>(atom_in, nbr_fea, nidx, WaT, b_3body, XB, WTA, WTE, k2scr);
  k3r_reduce<<<128, 256, 0, stream>>>(k2scr, ssum);
  k3p_params<<<1, 128, 0, stream>>>(ssum, g1, be1, ge, bee, g3, be3, params);
  k4a_main<<<NBLK, 256, 0, stream>>>(nbr_fea, nidx, b_full, b_edge, XB, WTA, WTE, params, tbuf, out_nbr);
  k4b_main<<<NBLK, 256, 0, stream>>>(atom_in, nbr_fea, nidx, WaT, b_3body, XB, WTA, WTE, params,
                                     tbuf, bn2scr);
  k5_reduce<<<128, 256, 0, stream>>>(bn2scr, bn2sum);
  k6_out<<<2000, 256, 0, stream>>>(atom_in, tbuf, bn2sum, g2, be2, out_atom);
}

// Round 11
// 169.200 us; speedup vs baseline: 1.0826x; 1.0826x over previous
//
#include <hip/hip_runtime.h>

typedef unsigned short u16;
typedef unsigned int u32;
typedef __attribute__((ext_vector_type(8))) short short8;
typedef __attribute__((ext_vector_type(4))) float f32x4;

#define NATOMS 8000
#define MNBR 12
#define EPSV 1e-5f
#define AB 4
#define ROWS 48
#define NBLK 2000
#define K2REC 1664

// u/v LDS buffer geometry (12 groups of 4 rows; group = 4*256B + 32B pad)
#define STG_B 12672
__device__ __forceinline__ int stg_idx(int row, int col) {  // u16 index
  return (row >> 2) * 528 + (row & 3) * 128 + col;
}

// ---- ws layout (bytes) ----
#define XB_OFF 0                 // u16 XB[8000][64] bf16 (1 MB, L2-resident)
#define WTA_OFF 1024000          // u16 WtAtom[768][64]
#define WTE_OFF 1122304          // u16 WtEdge[512][64]
#define WAT_OFF 1187840          // f32 WaT[128][64]
#define SSUM_OFF 1220608         // f32 ssum[1664] + bn2sum[128]
#define PARAMS_OFF 1227776       // f32 params[768]
#define TBUF_OFF 1230848         // f32 tbuf[8000*64]
#define WS_NEED 3278848

// ssum layout (f32 indices)
#define SS_BN1S 0
#define SS_BN1S2 128
#define SS_BNES 256
#define SS_BNES2 384
#define SS_U2 512
#define SS_V2 640
#define SS_A 768
#define SS_A2 896
#define SS_UB 1024
#define SS_VB 1152
#define SS_AU 1280
#define SS_AV 1408
#define SS_UV 1536

__device__ __forceinline__ u16 f2bf(float f) {
  u32 u = __float_as_uint(f);
  u += 0x7FFFu + ((u >> 16) & 1u);
  return (u16)(u >> 16);
}
__device__ __forceinline__ float bf2f(u16 h) { return __uint_as_float(((u32)h) << 16); }

__device__ __forceinline__ float sigf(float x) {
  return __builtin_amdgcn_rcpf(1.f + __expf(-x));
}
__device__ __forceinline__ float spf(float x) {
  return fmaxf(x, 0.f) + __logf(1.f + __expf(-fabsf(x)));
}

__device__ __forceinline__ void mfma16(f32x4 &acc, short8 a, short8 b) {
  asm volatile("v_mfma_f32_16x16x32_bf16 %0, %1, %2, %0" : "+v"(acc) : "v"(a), "v"(b));
}
__device__ __forceinline__ void accfence(f32x4 &a) {
  asm volatile("s_nop 7\ns_nop 7\ns_nop 7" : "+v"(a));
}
__device__ __forceinline__ void initfence(f32x4 &a) {
  asm volatile("s_nop 1" : "+v"(a));
}

// stage 16 f32 -> 16 bf16 into XOR-swizzled LDS row (row stride 128B)
__device__ __forceinline__ void stage_row16(short* lds, int row, int c16, const float* __restrict__ src) {
  const float4* s4 = reinterpret_cast<const float4*>(src);
  float4 q0 = s4[0], q1 = s4[1], q2 = s4[2], q3 = s4[3];
  short8 lo, hi;
  lo[0]=(short)f2bf(q0.x); lo[1]=(short)f2bf(q0.y); lo[2]=(short)f2bf(q0.z); lo[3]=(short)f2bf(q0.w);
  lo[4]=(short)f2bf(q1.x); lo[5]=(short)f2bf(q1.y); lo[6]=(short)f2bf(q1.z); lo[7]=(short)f2bf(q1.w);
  hi[0]=(short)f2bf(q2.x); hi[1]=(short)f2bf(q2.y); hi[2]=(short)f2bf(q2.z); hi[3]=(short)f2bf(q2.w);
  hi[4]=(short)f2bf(q3.x); hi[5]=(short)f2bf(q3.y); hi[6]=(short)f2bf(q3.z); hi[7]=(short)f2bf(q3.w);
  int base = row * 128 + c16 * 2;
  int sw = (row & 7) << 4;
  *reinterpret_cast<short8*>(reinterpret_cast<char*>(lds) + (base ^ sw)) = lo;
  *reinterpret_cast<short8*>(reinterpret_cast<char*>(lds) + ((base + 16) ^ sw)) = hi;
}

// stage x_j (48 edges) + x_own (4) bf16 rows from XB into swizzled xjT[64][64]
__device__ __forceinline__ void stage_xj(const u16* __restrict__ XB, const int* __restrict__ nidx,
                                         int eb, int ab, char* xjT, int t) {
  for (int s = t; s < 512; s += 256) {
    int r = s >> 3, j = s & 7;
    uint4 val = make_uint4(0u, 0u, 0u, 0u);
    if (r < 48) {
      int idx = nidx[eb + r];
      val = *reinterpret_cast<const uint4*>(XB + (size_t)idx * 64 + j * 8);
    } else if (r < 52) {
      val = *reinterpret_cast<const uint4*>(XB + (size_t)(ab + r - 48) * 64 + j * 8);
    }
    int off = (r * 128 + j * 16) ^ ((r & 7) << 4);
    *reinterpret_cast<uint4*>(xjT + off) = val;
  }
}

__device__ __forceinline__ short8 lds_afrag(const char* lds, int row, int kbyte) {
  int off = (row * 128 + kbyte) ^ ((row & 7) << 4);
  return *reinterpret_cast<const short8*>(lds + off);
}

// acc = xj@WTA[baseA..] + nbr@WTE[baseE..]  (48 rows x 128 cols, K=64)
template <int RT>
__device__ __forceinline__ void mfma_dual(const char* xjT, const char* nbrT,
                                          const u16* __restrict__ WTA, const u16* __restrict__ WTE,
                                          int baseA, int baseE, int w, int l,
                                          f32x4 (&acc)[RT][2]) {
  short8 ba[2][2], be[2][2];
#pragma unroll
  for (int p = 0; p < 2; ++p) {
    int colg = ((w + p * 4) << 4) + (l & 15);
#pragma unroll
    for (int kc = 0; kc < 2; ++kc) {
      ba[p][kc] = *reinterpret_cast<const short8*>(WTA + (size_t)(baseA + colg) * 64 + kc * 32 + ((l >> 4) << 3));
      be[p][kc] = *reinterpret_cast<const short8*>(WTE + (size_t)(baseE + colg) * 64 + kc * 32 + ((l >> 4) << 3));
    }
  }
#pragma unroll
  for (int rt = 0; rt < RT; ++rt)
#pragma unroll
    for (int p = 0; p < 2; ++p) { acc[rt][p] = f32x4{0.f, 0.f, 0.f, 0.f}; initfence(acc[rt][p]); }
#pragma unroll
  for (int rt = 0; rt < RT; ++rt) {
    int arow = rt * 16 + (l & 15);
    short8 x0 = lds_afrag(xjT, arow, (l >> 4) << 4);
    short8 x1 = lds_afrag(xjT, arow, 64 + ((l >> 4) << 4));
    short8 n0 = lds_afrag(nbrT, arow, (l >> 4) << 4);
    short8 n1 = lds_afrag(nbrT, arow, 64 + ((l >> 4) << 4));
#pragma unroll
    for (int p = 0; p < 2; ++p) {
      mfma16(acc[rt][p], x0, ba[p][0]);
      mfma16(acc[rt][p], x1, ba[p][1]);
      mfma16(acc[rt][p], n0, be[p][0]);
      mfma16(acc[rt][p], n1, be[p][1]);
    }
  }
#pragma unroll
  for (int rt = 0; rt < RT; ++rt)
#pragma unroll
    for (int p = 0; p < 2; ++p) accfence(acc[rt][p]);
}

// own projection: xjT rows 48-51 @ WTA[baseO..] -> ownv[4][128] f32 (per-wave cols)
__device__ __forceinline__ void mfma_own(const char* xjT, const u16* __restrict__ WTA,
                                         int baseO, int w, int l, float* ownv) {
  short8 bo[2][2];
#pragma unroll
  for (int p = 0; p < 2; ++p) {
    int colg = ((w + p * 4) << 4) + (l & 15);
#pragma unroll
    for (int kc = 0; kc < 2; ++kc)
      bo[p][kc] = *reinterpret_cast<const short8*>(WTA + (size_t)(baseO + colg) * 64 + kc * 32 + ((l >> 4) << 3));
  }
  int arow = 48 + (l & 15);
  short8 x0 = lds_afrag(xjT, arow, (l >> 4) << 4);
  short8 x1 = lds_afrag(xjT, arow, 64 + ((l >> 4) << 4));
  f32x4 acc[2];
#pragma unroll
  for (int p = 0; p < 2; ++p) {
    acc[p] = f32x4{0.f, 0.f, 0.f, 0.f};
    initfence(acc[p]);
    mfma16(acc[p], x0, bo[p][0]);
    mfma16(acc[p], x1, bo[p][1]);
  }
#pragma unroll
  for (int p = 0; p < 2; ++p) accfence(acc[p]);
  if (l < 16) {
    int col0 = (w << 4) + l;
#pragma unroll
    for (int r = 0; r < 4; ++r) {
      ownv[r * 128 + col0] = acc[0][r];
      ownv[r * 128 + col0 + 64] = acc[1][r];
    }
  }
}

// f32 a-term dot: dv[2] = xown[2h,2h+1] . WaT[c]
__device__ __forceinline__ void aterm_dot(const float* __restrict__ WaT, const float* xown,
                                          int c, int h, float& dv0, float& dv1) {
  const float4* wa4 = reinterpret_cast<const float4*>(WaT + (size_t)c * 64);
  const float4* x0 = reinterpret_cast<const float4*>(xown + (2 * h) * 64);
  const float4* x1 = reinterpret_cast<const float4*>(xown + (2 * h + 1) * 64);
  dv0 = 0.f; dv1 = 0.f;
#pragma unroll
  for (int q = 0; q < 16; ++q) {
    float4 wv = wa4[q], a4 = x0[q], b4 = x1[q];
    dv0 += a4.x * wv.x + a4.y * wv.y + a4.z * wv.z + a4.w * wv.w;
    dv1 += b4.x * wv.x + b4.y * wv.y + b4.z * wv.z + b4.w * wv.w;
  }
}

// ---------------- K0: XB + weight transposes + WaT + zero ssum ----------------
__global__ __launch_bounds__(256) void k0_prep(const float* __restrict__ atom_in,
                                               const float* __restrict__ W_full,
                                               const float* __restrict__ W_edge,
                                               const float* __restrict__ W_3body,
                                               u16* __restrict__ XB,
                                               u16* __restrict__ WTA, u16* __restrict__ WTE,
                                               float* __restrict__ WaT,
                                               float* __restrict__ ssum) {
  int t = blockIdx.x * 256 + threadIdx.x;
  if (t < 1792) ssum[t] = 0.f;
  if (t < 8192) { int c = t >> 6, k = t & 63; WaT[t] = W_3body[k * 128 + c]; }
  if (t < 49152) {
    int col = t >> 6, k = t & 63;
    int blk = col >> 7, c = col & 127;
    float v;
    switch (blk) {
      case 0: v = W_full[k * 128 + c]; break;
      case 1: v = W_full[(64 + k) * 128 + c]; break;
      case 2: v = W_edge[k * 128 + c]; break;
      case 3: v = W_edge[(64 + k) * 128 + c]; break;
      case 4: v = W_3body[(64 + k) * 128 + c]; break;
      default: v = W_3body[(128 + k) * 128 + c]; break;
    }
    WTA[t] = f2bf(v);
  } else if (t < 81920) {
    int u = t - 49152;
    int col = u >> 6, k = u & 63;
    int blk = col >> 7, c = col & 127;
    float v;
    switch (blk) {
      case 0: v = W_full[(128 + k) * 128 + c]; break;
      case 1: v = W_edge[(128 + k) * 128 + c]; break;
      case 2: v = W_3body[(192 + k) * 128 + c]; break;
      default: v = W_3body[(256 + k) * 128 + c]; break;
    }
    WTE[u] = f2bf(v);
  }
  if (t < NATOMS * 64) XB[t] = f2bf(atom_in[t]);
}

// ---------------- K2: all statistics (4 phases, merged) ----------------
__global__ __launch_bounds__(256, 4) void k2_stats(const float* __restrict__ atom_in,
                                                   const float* __restrict__ nbr_fea,
                                                   const int* __restrict__ nidx,
                                                   const float* __restrict__ WaT,
                                                   const float* __restrict__ b_full,
                                                   const float* __restrict__ b_edge,
                                                   const float* __restrict__ b_3body,
                                                   const u16* __restrict__ XB,
                                                   const u16* __restrict__ WTA,
                                                   const u16* __restrict__ WTE,
                                                   float* __restrict__ k2scr) {
  __shared__ __align__(16) char smem[25088];
  char* nbrT    = smem;                         // 6144
  char* xjT     = smem + 6144;                  // 8192
  float* ownv   = (float*)(smem + 14336);       // 2048
  float* ubar   = (float*)(smem + 16384);       // 2048
  float* vbar   = (float*)(smem + 18432);       // 2048
  float* xown   = (float*)(smem + 20480);       // 1024
  float* redscr = (float*)(smem + 21504);       // 3584
  int t = threadIdx.x, l = t & 63, w = t >> 6;
  int ab = blockIdx.x * AB, eb = ab * 12;
  float* sc = k2scr + (size_t)blockIdx.x * K2REC;

  for (int u = t; u < ROWS * 4; u += 256) {
    int row = u >> 2, c16 = (u & 3) * 16;
    stage_row16((short*)nbrT, row, c16, nbr_fea + (size_t)(eb + row) * 64 + c16);
  }
  stage_xj(XB, nidx, eb, ab, xjT, t);
  ubar[t] = 0.f; ubar[256 + t] = 0.f; vbar[t] = 0.f; vbar[256 + t] = 0.f;
  xown[t] = atom_in[(size_t)ab * 64 + t];
  __syncthreads();

  const int baseA[4] = {128, 384, 512, 640};
#pragma unroll
  for (int b = 0; b < 4; ++b) {
    f32x4 acc[3][2];
    mfma_dual<3>(xjT, nbrT, WTA, WTE, baseA[b], b * 128, w, l, acc);
    int col0 = (w << 4) + (l & 15), col1 = col0 + 64;
    int g = l >> 4;
    if (b < 2) {
      mfma_own(xjT, WTA, b ? 256 : 0, w, l, ownv);
      const float* bp = b ? b_edge : b_full;
      float bias0 = bp[col0], bias1 = bp[col1];
      float vs0 = 0.f, vs1 = 0.f, q0 = 0.f, q1 = 0.f;
#pragma unroll
      for (int rt = 0; rt < 3; ++rt) {
        int a12 = (rt * 16 + g * 4) / 12;
        float o0 = ownv[a12 * 128 + col0] + bias0;
        float o1 = ownv[a12 * 128 + col1] + bias1;
#pragma unroll
        for (int r = 0; r < 4; ++r) {
          float v0 = acc[rt][0][r] + o0;
          float v1 = acc[rt][1][r] + o1;
          vs0 += v0; q0 += v0 * v0; vs1 += v1; q1 += v1 * v1;
        }
      }
      vs0 += __shfl_xor(vs0, 16); vs0 += __shfl_xor(vs0, 32);
      vs1 += __shfl_xor(vs1, 16); vs1 += __shfl_xor(vs1, 32);
      q0 += __shfl_xor(q0, 16); q0 += __shfl_xor(q0, 32);
      q1 += __shfl_xor(q1, 16); q1 += __shfl_xor(q1, 32);
      if (l < 16) {
        int base = b ? 256 : 0;
        sc[base + col0] = vs0;
        sc[base + 128 + col0] = q0;
        sc[base + col1] = vs1;
        sc[base + 128 + col1] = q1;
      }
    } else {
      float* uvb = (b == 2) ? ubar : vbar;
      float q0 = 0.f, q1 = 0.f;
#pragma unroll
      for (int rt = 0; rt < 3; ++rt) {
        int a12 = (rt * 16 + g * 4) / 12;
        float s0 = 0.f, s1 = 0.f;
#pragma unroll
        for (int r = 0; r < 4; ++r) {
          float v0 = acc[rt][0][r];
          float v1 = acc[rt][1][r];
          s0 += v0; q0 += v0 * v0; s1 += v1; q1 += v1 * v1;
        }
        atomicAdd(&uvb[a12 * 128 + col0], s0);
        atomicAdd(&uvb[a12 * 128 + col1], s1);
      }
      q0 += __shfl_xor(q0, 16); q0 += __shfl_xor(q0, 32);
      q1 += __shfl_xor(q1, 16); q1 += __shfl_xor(q1, 32);
      if (l < 16) {
        int base = (b == 2) ? SS_U2 : SS_V2;
        sc[base + col0] = q0;
        sc[base + col1] = q1;
      }
    }
  }
  __syncthreads();

  // analytic bn3 partials
  {
    int c = t & 127, h = t >> 7;
    float dv0, dv1;
    aterm_dot(WaT, xown, c, h, dv0, dv1);
    float b3v = b_3body[c];
    float pA = 0.f, pA2 = 0.f, pUb = 0.f, pVb = 0.f, pAU = 0.f, pAV = 0.f, pUV = 0.f;
#pragma unroll
    for (int aa = 0; aa < 2; ++aa) {
      int a = 2 * h + aa;
      float aval = (aa ? dv1 : dv0) + b3v;
      float ub = ubar[a * 128 + c] * (1.f / 12.f);
      float vb = vbar[a * 128 + c] * (1.f / 12.f);
      pA += aval; pA2 += aval * aval; pUb += ub; pVb += vb;
      pAU += aval * ub; pAV += aval * vb; pUV += ub * vb;
    }
    if (h == 1) {
      float* rs = &redscr[c * 7];
      rs[0] = pA; rs[1] = pA2; rs[2] = pUb; rs[3] = pVb; rs[4] = pAU; rs[5] = pAV; rs[6] = pUV;
    }
    __syncthreads();
    if (h == 0) {
      const float* rs = &redscr[c * 7];
      sc[SS_A + c] = pA + rs[0];
      sc[SS_A2 + c] = pA2 + rs[1];
      sc[SS_UB + c] = pUb + rs[2];
      sc[SS_VB + c] = pVb + rs[3];
      sc[SS_AU + c] = pAU + rs[4];
      sc[SS_AV + c] = pAV + rs[5];
      sc[SS_UV + c] = pUV + rs[6];
    }
  }
}

// ---------------- K3r: reduce k2 scratch -> ssum ----------------
__global__ __launch_bounds__(256) void k3r_reduce(const float* __restrict__ k2scr,
                                                  float* __restrict__ ssum) {
  int cb = blockIdx.x & 1, ch = blockIdx.x >> 1;
  int f = cb * 256 + threadIdx.x;
  if (f >= K2REC / 4) return;
  int r0 = ch * 32;
  if (r0 >= NBLK) return;
  int r1 = min(r0 + 32, NBLK);
  float s0 = 0.f, s1 = 0.f, s2 = 0.f, s3 = 0.f;
#pragma unroll 8
  for (int r = r0; r < r1; ++r) {
    float4 v = *reinterpret_cast<const float4*>(k2scr + (size_t)r * K2REC + f * 4);
    s0 += v.x; s1 += v.y; s2 += v.z; s3 += v.w;
  }
  atomicAdd(&ssum[f * 4 + 0], s0);
  atomicAdd(&ssum[f * 4 + 1], s1);
  atomicAdd(&ssum[f * 4 + 2], s2);
  atomicAdd(&ssum[f * 4 + 3], s3);
}

// ---------------- K3p: finalize bn1/bne/bn3 affine params ----------------
__global__ void k3p_params(const float* __restrict__ ssum,
                           const float* __restrict__ g1, const float* __restrict__ be1,
                           const float* __restrict__ ge, const float* __restrict__ bee,
                           const float* __restrict__ g3, const float* __restrict__ be3,
                           float* __restrict__ params) {
  int c = threadIdx.x;
  if (c >= 128) return;
  const float cnt1 = 1.f / 96000.f;
  {
    float m = ssum[SS_BN1S + c] * cnt1;
    float var = ssum[SS_BN1S2 + c] * cnt1 - m * m;
    float s = g1[c] * rsqrtf(fmaxf(var, 0.f) + EPSV);
    params[c] = s; params[128 + c] = be1[c] - m * s;
  }
  {
    float m = ssum[SS_BNES + c] * cnt1;
    float var = ssum[SS_BNES2 + c] * cnt1 - m * m;
    float s = ge[c] * rsqrtf(fmaxf(var, 0.f) + EPSV);
    params[256 + c] = s; params[384 + c] = bee[c] - m * s;
  }
  {
    float Nf = (float)NATOMS;
    float A_ = ssum[SS_A + c], A2 = ssum[SS_A2 + c];
    float U2 = ssum[SS_U2 + c], V2 = ssum[SS_V2 + c];
    float Ub = ssum[SS_UB + c], Vb = ssum[SS_VB + c];
    float AU = ssum[SS_AU + c], AV = ssum[SS_AV + c], UV = ssum[SS_UV + c];
    float m = (A_ + Ub + Vb) / Nf;
    float ez2 = A2 / Nf + (U2 + V2) / (Nf * 12.f) + 2.f * (AU + AV + UV) / Nf;
    float var = ez2 - m * m;
    float s = g3[c] * rsqrtf(fmaxf(var, 0.f) + EPSV);
    params[512 + c] = s; params[640 + c] = be3[c] - m * s;
  }
}

// ---------------- K4: main pass (4 phases merged + 3-body + bn2) ----------------
__global__ __launch_bounds__(256, 4) void k4_main(const float* __restrict__ atom_in,
                                                  const float* __restrict__ nbr_fea,
                                                  const int* __restrict__ nidx,
                                                  const float* __restrict__ WaT,
                                                  const float* __restrict__ b_full,
                                                  const float* __restrict__ b_edge,
                                                  const float* __restrict__ b_3body,
                                                  const u16* __restrict__ XB,
                                                  const u16* __restrict__ WTA,
                                                  const u16* __restrict__ WTE,
                                                  const float* __restrict__ params,
                                                  float* __restrict__ tbuf,
                                                  float* __restrict__ out_nbr,
                                                  float* __restrict__ bn2scr) {
  __shared__ __align__(16) char smem[36224];
  char* nbrT      = smem;                         // 6144
  char* xjT       = smem + 6144;                  // 8192
  u16* u_s        = (u16*)(smem + 14336);         // 12672
  float* ownv     = (float*)(smem + 27008);       // 2048
  float* t2buf    = (float*)(smem + 29056);       // 1024
  float* params_s = (float*)(smem + 30080);       // 2048
  float* p3_s     = (float*)(smem + 32128);       // 1024
  float* a_s      = (float*)(smem + 33152);       // 2048
  float* xown     = (float*)(smem + 35200);       // 1024
  u16* v_s        = (u16*)smem;                   // alias nbrT+xjT (post b=3 MFMA)
  float* redscr2  = (float*)(smem + 14336);       // alias u_s (post 3-body)
  int t = threadIdx.x, l = t & 63, w = t >> 6;
  int ab = blockIdx.x * AB, eb = ab * 12;

  for (int u = t; u < ROWS * 4; u += 256) {
    int row = u >> 2, c16 = (u & 3) * 16;
    stage_row16((short*)nbrT, row, c16, nbr_fea + (size_t)(eb + row) * 64 + c16);
  }
  stage_xj(XB, nidx, eb, ab, xjT, t);
  xown[t] = atom_in[(size_t)ab * 64 + t];
  params_s[t] = params[t];
  params_s[t + 256] = params[t + 256];
  p3_s[t] = params[512 + t];
  t2buf[t] = 0.f;
  __syncthreads();

  // a' = (x_i @ Wa + b3) * s3 + t3 (f32)
  {
    int c = t & 127, h = t >> 7;
    float dv0, dv1;
    aterm_dot(WaT, xown, c, h, dv0, dv1);
    float s3 = p3_s[c], t3 = p3_s[128 + c];
    float b3v = b_3body[c];
    a_s[(2 * h) * 128 + c] = (dv0 + b3v) * s3 + t3;
    a_s[(2 * h + 1) * 128 + c] = (dv1 + b3v) * s3 + t3;
  }

  // phases b=0 (gates->t2buf), b=1 (gates->out_nbr)
#pragma unroll
  for (int b = 0; b < 2; ++b) {
    f32x4 acc[3][2];
    mfma_dual<3>(xjT, nbrT, WTA, WTE, b ? 384 : 128, b * 128, w, l, acc);
    mfma_own(xjT, WTA, b ? 256 : 0, w, l, ownv);
    int col0 = (w << 4) + (l & 15), col1 = col0 + 64;
    int g = l >> 4;
    const float* bp = b ? b_edge : b_full;
    float bias0 = bp[col0], bias1 = bp[col1];
    float sc0 = params_s[b * 256 + col0], sh0 = params_s[b * 256 + 128 + col0];
    float sc1 = params_s[b * 256 + col1], sh1 = params_s[b * 256 + 128 + col1];
#pragma unroll
    for (int rt = 0; rt < 3; ++rt) {
      int a12 = (rt * 16 + g * 4) / 12;
      float o0 = ownv[a12 * 128 + col0] + bias0;
      float o1 = ownv[a12 * 128 + col1] + bias1;
      float gsum = 0.f;
#pragma unroll
      for (int r = 0; r < 4; ++r) {
        int row = rt * 16 + g * 4 + r;
        float v0 = acc[rt][0][r] + o0;
        float v1 = acc[rt][1][r] + o1;
        float gate = sigf(v0 * sc0 + sh0) * spf(v1 * sc1 + sh1);
        if (b == 0) {
          gsum += gate;
        } else {
          size_t eg = (size_t)(eb + row) * 64 + col0;
          out_nbr[eg] = nbr_fea[eg] + gate;
        }
      }
      if (b == 0) atomicAdd(&t2buf[a12 * 64 + col0], gsum);
    }
  }

  // phase b=2 -> u_s
  {
    f32x4 acc[3][2];
    mfma_dual<3>(xjT, nbrT, WTA, WTE, 512, 256, w, l, acc);
    int col0 = (w << 4) + (l & 15), col1 = col0 + 64;
    int g = l >> 4;
    float s30 = p3_s[col0], s31 = p3_s[col1];
#pragma unroll
    for (int rt = 0; rt < 3; ++rt) {
#pragma unroll
      for (int r = 0; r < 4; ++r) {
        int row = rt * 16 + g * 4 + r;
        u_s[stg_idx(row, col0)] = f2bf(acc[rt][0][r] * s30);
        u_s[stg_idx(row, col1)] = f2bf(acc[rt][1][r] * s31);
      }
    }
  }
  // phase b=3 -> v_s (aliases nbrT/xjT; barrier after MFMA reads)
  {
    f32x4 acc[3][2];
    mfma_dual<3>(xjT, nbrT, WTA, WTE, 640, 384, w, l, acc);
    __syncthreads();  // all waves done reading nbrT/xjT (and t2buf adds done)
    int col0 = (w << 4) + (l & 15), col1 = col0 + 64;
    int g = l >> 4;
    float s30 = p3_s[col0], s31 = p3_s[col1];
#pragma unroll
    for (int rt = 0; rt < 3; ++rt) {
#pragma unroll
      for (int r = 0; r < 4; ++r) {
        int row = rt * 16 + g * 4 + r;
        v_s[stg_idx(row, col0)] = f2bf(acc[rt][0][r] * s30);
        v_s[stg_idx(row, col1)] = f2bf(acc[rt][1][r] * s31);
      }
    }
  }
  __syncthreads();

  // 3-body via exp factorization: sig(a+u+v) = rcp(1+E*F), sp = ln2*log2(1+G*H)
  float acc3 = 0.f;
  {
    int c = l, a = w;
    float af = a_s[a * 128 + c], ac = a_s[a * 128 + 64 + c];
    float Fl[12], Hl[12];
#pragma unroll
    for (int j2 = 0; j2 < 12; ++j2) {
      float vf = bf2f(v_s[stg_idx(a * 12 + j2, c)]);
      float vc = bf2f(v_s[stg_idx(a * 12 + j2, 64 + c)]);
      Fl[j2] = __expf(-vf);
      Hl[j2] = __expf(vc);
    }
    for (int j = 0; j < 12; ++j) {
      float uf = bf2f(u_s[stg_idx(a * 12 + j, c)]);
      float uc = bf2f(u_s[stg_idx(a * 12 + j, 64 + c)]);
      float Ej = __expf(-(af + uf));
      float Gj = __expf(ac + uc);
#pragma unroll
      for (int l2 = 0; l2 < 12; ++l2) {
        float p = fmaf(Ej, Fl[l2], 1.f);
        float q = fmaf(Gj, Hl[l2], 1.f);
        acc3 += __builtin_amdgcn_rcpf(p) * __log2f(q);
      }
    }
  }
  __syncthreads();

  // t = two + three body; bn2 partials (column-major scratch)
  {
    float x = t2buf[t] + acc3 * 0.6931471805599453f;
    tbuf[(size_t)(ab + w) * 64 + l] = x;
    redscr2[t] = x;
    redscr2[256 + t] = x * x;
    __syncthreads();
    if (t < 64) {
      float s = redscr2[t] + redscr2[t + 64] + redscr2[t + 128] + redscr2[t + 192];
      float s2 = redscr2[256 + t] + redscr2[256 + t + 64] + redscr2[256 + t + 128] + redscr2[256 + t + 192];
      bn2scr[(size_t)t * 2048 + blockIdx.x] = s;
      bn2scr[(size_t)(64 + t) * 2048 + blockIdx.x] = s2;
    }
  }
}

// ---------------- K5: reduce bn2 partials -> bn2sum[128] ----------------
__global__ __launch_bounds__(256) void k5_reduce(const float* __restrict__ bn2scr,
                                                 float* __restrict__ bn2sum) {
  __shared__ float wsum[4];
  int c = blockIdx.x, t = threadIdx.x;
  float s = 0.f;
#pragma unroll 4
  for (int i = t; i < NBLK; i += 256) s += bn2scr[(size_t)c * 2048 + i];
  s += __shfl_xor(s, 1); s += __shfl_xor(s, 2); s += __shfl_xor(s, 4);
  s += __shfl_xor(s, 8); s += __shfl_xor(s, 16); s += __shfl_xor(s, 32);
  if ((t & 63) == 0) wsum[t >> 6] = s;
  __syncthreads();
  if (t == 0) bn2sum[c] = wsum[0] + wsum[1] + wsum[2] + wsum[3];
}

// ---------------- K6: bn2 + final softplus ----------------
__global__ __launch_bounds__(256) void k6_out(const float* __restrict__ atom_in,
                                              const float* __restrict__ tbuf,
                                              const float* __restrict__ bn2sum,
                                              const float* __restrict__ g2,
                                              const float* __restrict__ be2,
                                              float* __restrict__ out_atom) {
  __shared__ float sc[64], sh[64];
  int t = threadIdx.x;
  if (t < 64) {
    float S = bn2sum[t], S2 = bn2sum[64 + t];
    float m = S * (1.f / (float)NATOMS);
    float var = S2 * (1.f / (float)NATOMS) - m * m;
    float s = g2[t] * rsqrtf(fmaxf(var, 0.f) + EPSV);
    sc[t] = s; sh[t] = be2[t] - m * s;
  }
  __syncthreads();
  int i = blockIdx.x * 256 + t;
  if (i < NATOMS * 64) {
    int c = i & 63;
    float v = atom_in[i] + tbuf[i] * sc[c] + sh[c];
    out_atom[i] = spf(v);
  }
}

extern "C" void kernel_launch(void* const* d_in, const int* in_sizes, int n_in,
                              void* d_out, int out_size, void* d_ws, size_t ws_size,
                              hipStream_t stream) {
  if (ws_size < (size_t)WS_NEED) return;
  const float* atom_in = (const float*)d_in[0];
  const float* nbr_fea = (const float*)d_in[1];
  const int* nidx = (const int*)d_in[2];
  const float* W_full = (const float*)d_in[3];
  const float* b_full = (const float*)d_in[4];
  const float* g1 = (const float*)d_in[5];
  const float* be1 = (const float*)d_in[6];
  const float* W_edge = (const float*)d_in[7];
  const float* b_edge = (const float*)d_in[8];
  const float* ge = (const float*)d_in[9];
  const float* bee = (const float*)d_in[10];
  const float* W_3body = (const float*)d_in[11];
  const float* b_3body = (const float*)d_in[12];
  const float* g3 = (const float*)d_in[13];
  const float* be3 = (const float*)d_in[14];
  const float* g2 = (const float*)d_in[15];
  const float* be2 = (const float*)d_in[16];

  char* ws = (char*)d_ws;
  u16* XB = (u16*)(ws + XB_OFF);
  u16* WTA = (u16*)(ws + WTA_OFF);
  u16* WTE = (u16*)(ws + WTE_OFF);
  float* WaT = (float*)(ws + WAT_OFF);
  float* ssum = (float*)(ws + SSUM_OFF);
  float* bn2sum = ssum + K2REC;
  float* params = (float*)(ws + PARAMS_OFF);
  float* tbuf = (float*)(ws + TBUF_OFF);

  float* out_atom = (float*)d_out;
  float* out_nbr = out_atom + NATOMS * 64;
  float* k2scr = out_nbr;    // scratch until k4 overwrites
  float* bn2scr = out_atom;  // scratch until k6 overwrites

  k0_prep<<<2000, 256, 0, stream>>>(atom_in, W_full, W_edge, W_3body, XB, WTA, WTE, WaT, ssum);
  k2_stats<<<NBLK, 256, 0, stream>>>(atom_in, nbr_fea, nidx, WaT, b_full, b_edge, b_3body,
                                     XB, WTA, WTE, k2scr);
  k3r_reduce<<<128, 256, 0, stream>>>(k2scr, ssum);
  k3p_params<<<1, 128, 0, stream>>>(ssum, g1, be1, ge, bee, g3, be3, params);
  k4_main<<<NBLK, 256, 0, stream>>>(atom_in, nbr_fea, nidx, WaT, b_full, b_edge, b_3body,
                                    XB, WTA, WTE, params, tbuf, out_nbr, bn2scr);
  k5_reduce<<<128, 256, 0, stream>>>(bn2scr, bn2sum);
  k6_out<<<2000, 256, 0, stream>>>(atom_in, tbuf, bn2sum, g2, be2, out_atom);
}

// Round 12
// 164.324 us; speedup vs baseline: 1.1147x; 1.0297x over previous
//
#include <hip/hip_runtime.h>

typedef unsigned short u16;
typedef unsigned int u32;
typedef __attribute__((ext_vector_type(8))) short short8;
typedef __attribute__((ext_vector_type(4))) float f32x4;

#define NATOMS 8000
#define MNBR 12
#define EPSV 1e-5f
#define AB 4
#define ROWS 48
#define NBLK 2000      // k4 blocks
#define NZG 500        // kzg blocks (16 atoms each)
#define KREC 1408      // stats record floats per kzg block

// u/v LDS buffer geometry (k4; 12 groups of 4 rows; group = 4*256B + 32B pad)
#define STG_B 12672
__device__ __forceinline__ int stg_idx(int row, int col) {  // u16 index
  return (row >> 2) * 528 + (row & 3) * 128 + col;
}

// ---- ws layout (bytes) ----
#define XB_OFF 0                 // u16 XB[8000][64]
#define WTA_OFF 1024000          // u16 WtAtom[896][64] (block6 = Wa)
#define WTE_OFF 1138688          // u16 WtEdge[512][64]
#define WAT_OFF 1204224          // f32 WaT[128][64]
#define MREP_OFF 1236992         // f32 Mrep[8][128][128]
#define MFIN_OFF 1761280         // f32 M[128][128]
#define QF4_OFF 1826816          // f32 qf4[4][128]
#define SSUM_OFF 1828864         // f32 ssum[1408] + bn2sum[128]
#define PARAMS_OFF 1835008       // f32 params[768]
#define TBUF_OFF 1838080         // f32 tbuf[8000*64]
#define WS_NEED 3886080

// ssum layout (f32 indices) == record layout
#define SS_BN1S 0
#define SS_BN1S2 128
#define SS_BNES 256
#define SS_BNES2 384
#define SS_A 512
#define SS_A2 640
#define SS_UB 768
#define SS_VB 896
#define SS_AU 1024
#define SS_AV 1152
#define SS_UV 1280

__device__ __forceinline__ u16 f2bf(float f) {
  u32 u = __float_as_uint(f);
  u += 0x7FFFu + ((u >> 16) & 1u);
  return (u16)(u >> 16);
}
__device__ __forceinline__ float bf2f(u16 h) { return __uint_as_float(((u32)h) << 16); }

__device__ __forceinline__ float sigf(float x) {
  return __builtin_amdgcn_rcpf(1.f + __expf(-x));
}
__device__ __forceinline__ float spf(float x) {
  return fmaxf(x, 0.f) + __logf(1.f + __expf(-fabsf(x)));
}

__device__ __forceinline__ void mfma16(f32x4 &acc, short8 a, short8 b) {
  asm volatile("v_mfma_f32_16x16x32_bf16 %0, %1, %2, %0" : "+v"(acc) : "v"(a), "v"(b));
}
__device__ __forceinline__ void accfence(f32x4 &a) {
  asm volatile("s_nop 7\ns_nop 7\ns_nop 7" : "+v"(a));
}
__device__ __forceinline__ void initfence(f32x4 &a) {
  asm volatile("s_nop 1" : "+v"(a));
}

// stage 16 f32 -> 16 bf16 into XOR-swizzled LDS row (row stride 128B)
__device__ __forceinline__ void stage_row16(short* lds, int row, int c16, const float* __restrict__ src) {
  const float4* s4 = reinterpret_cast<const float4*>(src);
  float4 q0 = s4[0], q1 = s4[1], q2 = s4[2], q3 = s4[3];
  short8 lo, hi;
  lo[0]=(short)f2bf(q0.x); lo[1]=(short)f2bf(q0.y); lo[2]=(short)f2bf(q0.z); lo[3]=(short)f2bf(q0.w);
  lo[4]=(short)f2bf(q1.x); lo[5]=(short)f2bf(q1.y); lo[6]=(short)f2bf(q1.z); lo[7]=(short)f2bf(q1.w);
  hi[0]=(short)f2bf(q2.x); hi[1]=(short)f2bf(q2.y); hi[2]=(short)f2bf(q2.z); hi[3]=(short)f2bf(q2.w);
  hi[4]=(short)f2bf(q3.x); hi[5]=(short)f2bf(q3.y); hi[6]=(short)f2bf(q3.z); hi[7]=(short)f2bf(q3.w);
  int base = row * 128 + c16 * 2;
  int sw = (row & 7) << 4;
  *reinterpret_cast<short8*>(reinterpret_cast<char*>(lds) + (base ^ sw)) = lo;
  *reinterpret_cast<short8*>(reinterpret_cast<char*>(lds) + ((base + 16) ^ sw)) = hi;
}

// stage x_j (48 edges) + x_own (4) bf16 rows from XB into swizzled xjT[64][64]
__device__ __forceinline__ void stage_xj(const u16* __restrict__ XB, const int* __restrict__ nidx,
                                         int eb, int ab, char* xjT, int t) {
  for (int s = t; s < 512; s += 256) {
    int r = s >> 3, j = s & 7;
    uint4 val = make_uint4(0u, 0u, 0u, 0u);
    if (r < 48) {
      int idx = nidx[eb + r];
      val = *reinterpret_cast<const uint4*>(XB + (size_t)idx * 64 + j * 8);
    } else if (r < 52) {
      val = *reinterpret_cast<const uint4*>(XB + (size_t)(ab + r - 48) * 64 + j * 8);
    }
    int off = (r * 128 + j * 16) ^ ((r & 7) << 4);
    *reinterpret_cast<uint4*>(xjT + off) = val;
  }
}

__device__ __forceinline__ short8 lds_afrag(const char* lds, int row, int kbyte) {
  int off = (row * 128 + kbyte) ^ ((row & 7) << 4);
  return *reinterpret_cast<const short8*>(lds + off);
}

// scalar swizzled u16 access (zT staging / reads)
__device__ __forceinline__ void zt_w16(char* zT, int chan, int e, u16 v) {
  int off = (chan * 128 + e * 2) ^ ((chan & 7) << 4);
  *reinterpret_cast<u16*>(zT + off) = v;
}
__device__ __forceinline__ u16 zt_r16(const char* zT, int chan, int e) {
  int off = (chan * 128 + e * 2) ^ ((chan & 7) << 4);
  return *reinterpret_cast<const u16*>(zT + off);
}

// acc = xj@WTA[baseA..] + nbr@WTE[baseE..]
template <int RT>
__device__ __forceinline__ void mfma_dual(const char* xjT, const char* nbrT,
                                          const u16* __restrict__ WTA, const u16* __restrict__ WTE,
                                          int baseA, int baseE, int w, int l,
                                          f32x4 (&acc)[RT][2]) {
  short8 ba[2][2], be[2][2];
#pragma unroll
  for (int p = 0; p < 2; ++p) {
    int colg = ((w + p * 4) << 4) + (l & 15);
#pragma unroll
    for (int kc = 0; kc < 2; ++kc) {
      ba[p][kc] = *reinterpret_cast<const short8*>(WTA + (size_t)(baseA + colg) * 64 + kc * 32 + ((l >> 4) << 3));
      be[p][kc] = *reinterpret_cast<const short8*>(WTE + (size_t)(baseE + colg) * 64 + kc * 32 + ((l >> 4) << 3));
    }
  }
#pragma unroll
  for (int rt = 0; rt < RT; ++rt)
#pragma unroll
    for (int p = 0; p < 2; ++p) { acc[rt][p] = f32x4{0.f, 0.f, 0.f, 0.f}; initfence(acc[rt][p]); }
#pragma unroll
  for (int rt = 0; rt < RT; ++rt) {
    int arow = rt * 16 + (l & 15);
    short8 x0 = lds_afrag(xjT, arow, (l >> 4) << 4);
    short8 x1 = lds_afrag(xjT, arow, 64 + ((l >> 4) << 4));
    short8 n0 = lds_afrag(nbrT, arow, (l >> 4) << 4);
    short8 n1 = lds_afrag(nbrT, arow, 64 + ((l >> 4) << 4));
#pragma unroll
    for (int p = 0; p < 2; ++p) {
      mfma16(acc[rt][p], x0, ba[p][0]);
      mfma16(acc[rt][p], x1, ba[p][1]);
      mfma16(acc[rt][p], n0, be[p][0]);
      mfma16(acc[rt][p], n1, be[p][1]);
    }
  }
#pragma unroll
  for (int rt = 0; rt < RT; ++rt)
#pragma unroll
    for (int p = 0; p < 2; ++p) accfence(acc[rt][p]);
}

// acc = aT@WTA[baseC..]  (single-operand variant)
template <int RT>
__device__ __forceinline__ void mfma_single(const char* aT, const u16* __restrict__ WTA,
                                            int baseC, int w, int l, f32x4 (&acc)[RT][2]) {
  short8 bw[2][2];
#pragma unroll
  for (int p = 0; p < 2; ++p) {
    int colg = ((w + p * 4) << 4) + (l & 15);
#pragma unroll
    for (int kc = 0; kc < 2; ++kc)
      bw[p][kc] = *reinterpret_cast<const short8*>(WTA + (size_t)(baseC + colg) * 64 + kc * 32 + ((l >> 4) << 3));
  }
#pragma unroll
  for (int rt = 0; rt < RT; ++rt)
#pragma unroll
    for (int p = 0; p < 2; ++p) { acc[rt][p] = f32x4{0.f, 0.f, 0.f, 0.f}; initfence(acc[rt][p]); }
#pragma unroll
  for (int rt = 0; rt < RT; ++rt) {
    int arow = rt * 16 + (l & 15);
    short8 x0 = lds_afrag(aT, arow, (l >> 4) << 4);
    short8 x1 = lds_afrag(aT, arow, 64 + ((l >> 4) << 4));
#pragma unroll
    for (int p = 0; p < 2; ++p) {
      mfma16(acc[rt][p], x0, bw[p][0]);
      mfma16(acc[rt][p], x1, bw[p][1]);
    }
  }
#pragma unroll
  for (int rt = 0; rt < RT; ++rt)
#pragma unroll
    for (int p = 0; p < 2; ++p) accfence(acc[rt][p]);
}

// own projection (k4): xjT rows 48-51 @ WTA[baseO..] -> ownv[4][128] f32
__device__ __forceinline__ void mfma_own(const char* xjT, const u16* __restrict__ WTA,
                                         int baseO, int w, int l, float* ownv) {
  short8 bo[2][2];
#pragma unroll
  for (int p = 0; p < 2; ++p) {
    int colg = ((w + p * 4) << 4) + (l & 15);
#pragma unroll
    for (int kc = 0; kc < 2; ++kc)
      bo[p][kc] = *reinterpret_cast<const short8*>(WTA + (size_t)(baseO + colg) * 64 + kc * 32 + ((l >> 4) << 3));
  }
  int arow = 48 + (l & 15);
  short8 x0 = lds_afrag(xjT, arow, (l >> 4) << 4);
  short8 x1 = lds_afrag(xjT, arow, 64 + ((l >> 4) << 4));
  f32x4 acc[2];
#pragma unroll
  for (int p = 0; p < 2; ++p) {
    acc[p] = f32x4{0.f, 0.f, 0.f, 0.f};
    initfence(acc[p]);
    mfma16(acc[p], x0, bo[p][0]);
    mfma16(acc[p], x1, bo[p][1]);
  }
#pragma unroll
  for (int p = 0; p < 2; ++p) accfence(acc[p]);
  if (l < 16) {
    int col0 = (w << 4) + l;
#pragma unroll
    for (int r = 0; r < 4; ++r) {
      ownv[r * 128 + col0] = acc[0][r];
      ownv[r * 128 + col0 + 64] = acc[1][r];
    }
  }
}

// f32 a-term dot (k4): dv[2] = xown[2h,2h+1] . WaT[c]
__device__ __forceinline__ void aterm_dot(const float* __restrict__ WaT, const float* xown,
                                          int c, int h, float& dv0, float& dv1) {
  const float4* wa4 = reinterpret_cast<const float4*>(WaT + (size_t)c * 64);
  const float4* x0 = reinterpret_cast<const float4*>(xown + (2 * h) * 64);
  const float4* x1 = reinterpret_cast<const float4*>(xown + (2 * h + 1) * 64);
  dv0 = 0.f; dv1 = 0.f;
#pragma unroll
  for (int q = 0; q < 16; ++q) {
    float4 wv = wa4[q], a4 = x0[q], b4 = x1[q];
    dv0 += a4.x * wv.x + a4.y * wv.y + a4.z * wv.z + a4.w * wv.w;
    dv1 += b4.x * wv.x + b4.y * wv.y + b4.z * wv.z + b4.w * wv.w;
  }
}

// ---------------- K0: XB + weight transposes + WaT + zero ssum/Mrep ----------------
__global__ __launch_bounds__(256) void k0_prep(const float* __restrict__ atom_in,
                                               const float* __restrict__ W_full,
                                               const float* __restrict__ W_edge,
                                               const float* __restrict__ W_3body,
                                               u16* __restrict__ XB,
                                               u16* __restrict__ WTA, u16* __restrict__ WTE,
                                               float* __restrict__ WaT,
                                               float* __restrict__ Mrep,
                                               float* __restrict__ ssum) {
  int t = blockIdx.x * 256 + threadIdx.x;
  if (t < 1536) ssum[t] = 0.f;
  if (t < 131072) Mrep[t] = 0.f;
  if (t < 8192) { int c = t >> 6, k = t & 63; WaT[t] = W_3body[k * 128 + c]; }
  if (t < 57344) {  // WtAtom: 896 cols x 64 k
    int col = t >> 6, k = t & 63;
    int blk = col >> 7, c = col & 127;
    float v;
    switch (blk) {
      case 0: v = W_full[k * 128 + c]; break;
      case 1: v = W_full[(64 + k) * 128 + c]; break;
      case 2: v = W_edge[k * 128 + c]; break;
      case 3: v = W_edge[(64 + k) * 128 + c]; break;
      case 4: v = W_3body[(64 + k) * 128 + c]; break;
      case 5: v = W_3body[(128 + k) * 128 + c]; break;
      default: v = W_3body[k * 128 + c]; break;  // Wa
    }
    WTA[t] = f2bf(v);
  } else if (t < 57344 + 32768) {  // WtEdge: 512 cols x 64 k
    int u = t - 57344;
    int col = u >> 6, k = u & 63;
    int blk = col >> 7, c = col & 127;
    float v;
    switch (blk) {
      case 0: v = W_full[(128 + k) * 128 + c]; break;
      case 1: v = W_edge[(128 + k) * 128 + c]; break;
      case 2: v = W_3body[(192 + k) * 128 + c]; break;
      default: v = W_3body[(256 + k) * 128 + c]; break;
    }
    WTE[u] = f2bf(v);
  }
  if (t < NATOMS * 64) XB[t] = f2bf(atom_in[t]);
}

// ---------------- KZG: Gram M + per-atom stats (16 atoms/block) ----------------
__global__ __launch_bounds__(256, 4) void kzg_stats(const float* __restrict__ nbr_fea,
                                                    const int* __restrict__ nidx,
                                                    const float* __restrict__ b_full,
                                                    const float* __restrict__ b_edge,
                                                    const float* __restrict__ b_3body,
                                                    const u16* __restrict__ XB,
                                                    const u16* __restrict__ WTA,
                                                    const u16* __restrict__ WTE,
                                                    float* __restrict__ Mrep,
                                                    float* __restrict__ krec) {
  __shared__ __align__(16) char smem[30720];
  char* zT       = smem;                      // 16384 (128 chan x 64 edge-k, swizzled)
  char* xT       = smem + 16384;              // 2048
  char* ZxT      = smem + 18432;              // 2048
  char* ZnT      = smem + 20480;              // 2048
  float* Zbar    = (float*)(smem + 22528);    // 8192: [16 atoms][128 chan]
  int t = threadIdx.x, l = t & 63, w = t >> 6;
  int bid = blockIdx.x;
  int ab = bid * 16;
  float* sc = krec + (size_t)bid * KREC;

  // stage xT (16 atom rows)
  if (t < 128) {
    int row = t >> 3, j = t & 7;
    uint4 val = *reinterpret_cast<const uint4*>(XB + (size_t)(ab + row) * 64 + j * 8);
    int off = (row * 128 + j * 16) ^ ((row & 7) << 4);
    *reinterpret_cast<uint4*>(xT + off) = val;
  }
  // zero Zbar
  for (int s = t; s < 2048; s += 256) Zbar[s] = 0.f;
  // zero zT k-tail (48..63) once
  for (int s = t; s < 512; s += 256) {
    int chan = s >> 2, kq = 48 + (s & 3) * 4;
    int off = (chan * 128 + kq * 2) ^ ((chan & 7) << 4);
    *reinterpret_cast<uint2*>(zT + off) = make_uint2(0u, 0u);
  }

  f32x4 gacc[2][8];
#pragma unroll
  for (int h = 0; h < 2; ++h)
#pragma unroll
    for (int q = 0; q < 8; ++q) { gacc[h][q] = f32x4{0.f, 0.f, 0.f, 0.f}; initfence(gacc[h][q]); }

  for (int c4 = 0; c4 < 4; ++c4) {
    __syncthreads();  // prior reads done / init done
    int ebg = (ab + c4 * 4) * 12;
    // stage x_j part (chans 0..63) transposed
    for (int s = t; s < 384; s += 256) {
      int r = s >> 3, j = s & 7;
      int idx = nidx[ebg + r];
      uint4 val = *reinterpret_cast<const uint4*>(XB + (size_t)idx * 64 + j * 8);
      const u16* v8 = reinterpret_cast<const u16*>(&val);
#pragma unroll
      for (int q2 = 0; q2 < 8; ++q2) zt_w16(zT, j * 8 + q2, r, v8[q2]);
    }
    // stage nbr part (chans 64..127)
    for (int s = t; s < 768; s += 256) {
      int e = s >> 4, cq = (s & 15) * 4;
      float4 v = *reinterpret_cast<const float4*>(nbr_fea + (size_t)(ebg + e) * 64 + cq);
      zt_w16(zT, 64 + cq + 0, e, f2bf(v.x));
      zt_w16(zT, 64 + cq + 1, e, f2bf(v.y));
      zt_w16(zT, 64 + cq + 2, e, f2bf(v.z));
      zt_w16(zT, 64 + cq + 3, e, f2bf(v.w));
    }
    __syncthreads();
    // Gram accumulate: wave w owns row-blocks {w, w+4} x 8 col-blocks
#pragma unroll
    for (int h = 0; h < 2; ++h) {
      int ta = w + h * 4;
      short8 a0 = lds_afrag(zT, ta * 16 + (l & 15), (l >> 4) << 4);
      short8 a1 = lds_afrag(zT, ta * 16 + (l & 15), 64 + ((l >> 4) << 4));
#pragma unroll
      for (int q = 0; q < 8; ++q) {
        short8 b0 = lds_afrag(zT, q * 16 + (l & 15), (l >> 4) << 4);
        short8 b1 = lds_afrag(zT, q * 16 + (l & 15), 64 + ((l >> 4) << 4));
        mfma16(gacc[h][q], a0, b0);
        mfma16(gacc[h][q], a1, b1);
      }
    }
    // Zbar accumulate (each thread owns 2 (atom,chan) slots)
    for (int s = t; s < 512; s += 256) {
      int a4 = s >> 7, c = s & 127;
      float acc = 0.f;
#pragma unroll
      for (int m = 0; m < 12; ++m) acc += bf2f(zt_r16(zT, c, a4 * 12 + m));
      Zbar[(c4 * 4 + a4) * 128 + c] += acc;
    }
  }
#pragma unroll
  for (int h = 0; h < 2; ++h)
#pragma unroll
    for (int q = 0; q < 8; ++q) accfence(gacc[h][q]);

  // flush Gram partials (8 replicas)
  float* Md = Mrep + (size_t)(bid & 7) * 16384;
#pragma unroll
  for (int h = 0; h < 2; ++h) {
    int ta = w + h * 4;
#pragma unroll
    for (int q = 0; q < 8; ++q)
#pragma unroll
      for (int r = 0; r < 4; ++r) {
        int Mrow = ta * 16 + (l >> 4) * 4 + r;
        int Mcol = q * 16 + (l & 15);
        atomicAdd(&Md[Mrow * 128 + Mcol], gacc[h][q][r]);
      }
  }

  __syncthreads();  // Zbar complete
  // stage ZxT / ZnT (bf16, swizzled) from Zbar
  {
    int row = t >> 4, kq = (t & 15) * 4;
    const float* zr = &Zbar[row * 128 + kq];
    u16 vx[4], vn[4];
#pragma unroll
    for (int i = 0; i < 4; ++i) { vx[i] = f2bf(zr[i]); vn[i] = f2bf(zr[64 + i]); }
    int off = (row * 128 + kq * 2) ^ ((row & 7) << 4);
    *reinterpret_cast<uint2*>(ZxT + off) = *reinterpret_cast<uint2*>(vx);
    *reinterpret_cast<uint2*>(ZnT + off) = *reinterpret_cast<uint2*>(vn);
  }
  __syncthreads();

  // 7 projection phases (16 atom rows)
  f32x4 qf[1][2], qe[1][2], qu[1][2], qv[1][2], o1[1][2], oe[1][2], a3[1][2];
  mfma_dual<1>(ZxT, ZnT, WTA, WTE, 128, 0, w, l, qf);
  mfma_dual<1>(ZxT, ZnT, WTA, WTE, 384, 128, w, l, qe);
  mfma_dual<1>(ZxT, ZnT, WTA, WTE, 512, 256, w, l, qu);
  mfma_dual<1>(ZxT, ZnT, WTA, WTE, 640, 384, w, l, qv);
  mfma_single<1>(xT, WTA, 0, w, l, o1);
  mfma_single<1>(xT, WTA, 256, w, l, oe);
  mfma_single<1>(xT, WTA, 768, w, l, a3);

  // per-column stats over 16 atoms
#pragma unroll
  for (int p = 0; p < 2; ++p) {
    int col = (w << 4) + (l & 15) + p * 64;
    float bf = b_full[col], be_ = b_edge[col], b3 = b_3body[col];
    float s1 = 0.f, s1q = 0.f, se = 0.f, seq = 0.f;
    float A = 0.f, A2 = 0.f, UB = 0.f, VB = 0.f, AU = 0.f, AV = 0.f, UV = 0.f;
#pragma unroll
    for (int r = 0; r < 4; ++r) {
      float o = o1[0][p][r] + bf;
      float q = qf[0][p][r];
      s1 += 12.f * o + q; s1q += 12.f * o * o + 2.f * o * q;
      float oev = oe[0][p][r] + be_;
      float qev = qe[0][p][r];
      se += 12.f * oev + qev; seq += 12.f * oev * oev + 2.f * oev * qev;
      float av = a3[0][p][r] + b3;
      float ub = qu[0][p][r] * (1.f / 12.f);
      float vb = qv[0][p][r] * (1.f / 12.f);
      A += av; A2 += av * av; UB += ub; VB += vb;
      AU += av * ub; AV += av * vb; UV += ub * vb;
    }
    float st[11] = {s1, s1q, se, seq, A, A2, UB, VB, AU, AV, UV};
#pragma unroll
    for (int i = 0; i < 11; ++i) {
      st[i] += __shfl_xor(st[i], 16);
      st[i] += __shfl_xor(st[i], 32);
    }
    if (l < 16) {
      sc[SS_BN1S + col] = st[0];
      sc[SS_BN1S2 + col] = st[1];
      sc[SS_BNES + col] = st[2];
      sc[SS_BNES2 + col] = st[3];
      sc[SS_A + col] = st[4];
      sc[SS_A2 + col] = st[5];
      sc[SS_UB + col] = st[6];
      sc[SS_VB + col] = st[7];
      sc[SS_AU + col] = st[8];
      sc[SS_AV + col] = st[9];
      sc[SS_UV + col] = st[10];
    }
  }
}

// ---------------- K3r: reduce records (500 x 1408) -> ssum; Mrep -> Mfin ----------------
__global__ __launch_bounds__(256) void k3r_reduce(const float* __restrict__ krec,
                                                  const float* __restrict__ Mrep,
                                                  float* __restrict__ ssum,
                                                  float* __restrict__ Mfin) {
  int bid = blockIdx.x, t = threadIdx.x;
  if (bid < 20) {
    int cb = bid & 1, chunk = bid >> 1;
    int f = cb * 256 + t;
    if (f >= KREC / 4) return;
    int r0 = chunk * 50, r1 = r0 + 50;
    float s0 = 0.f, s1 = 0.f, s2 = 0.f, s3 = 0.f;
#pragma unroll 5
    for (int r = r0; r < r1; ++r) {
      float4 v = *reinterpret_cast<const float4*>(krec + (size_t)r * KREC + f * 4);
      s0 += v.x; s1 += v.y; s2 += v.z; s3 += v.w;
    }
    atomicAdd(&ssum[f * 4 + 0], s0);
    atomicAdd(&ssum[f * 4 + 1], s1);
    atomicAdd(&ssum[f * 4 + 2], s2);
    atomicAdd(&ssum[f * 4 + 3], s3);
  } else {
    int idx = (bid - 20) * 256 + t;
    if (idx >= 16384) return;
    float s = 0.f;
#pragma unroll
    for (int rep = 0; rep < 8; ++rep) s += Mrep[(size_t)rep * 16384 + idx];
    Mfin[idx] = s;
  }
}

// ---------------- K3q: quadratic forms w^T M w (128 blocks x 128 thr) ----------------
__global__ __launch_bounds__(128) void k3q_qf(const float* __restrict__ M,
                                              const float* __restrict__ W_full,
                                              const float* __restrict__ W_edge,
                                              const float* __restrict__ W_3body,
                                              float* __restrict__ qf4) {
  __shared__ float wv[128];
  __shared__ float red[2];
  int c = blockIdx.x, t = threadIdx.x;
#pragma unroll
  for (int sel = 0; sel < 4; ++sel) {
    float wval;
    if (sel == 0) wval = (t < 64) ? W_full[(64 + t) * 128 + c] : W_full[(64 + t) * 128 + c];
    else if (sel == 1) wval = W_edge[(64 + t) * 128 + c];
    else if (sel == 2) wval = (t < 64) ? W_3body[(64 + t) * 128 + c] : W_3body[(128 + t) * 128 + c];
    else wval = (t < 64) ? W_3body[(128 + t) * 128 + c] : W_3body[(192 + t) * 128 + c];
    wv[t] = wval;
    __syncthreads();
    // y_t = M[row t] . wv  (M symmetric)
    float y = 0.f;
    const float4* mr = reinterpret_cast<const float4*>(M + (size_t)t * 128);
#pragma unroll 8
    for (int q2 = 0; q2 < 32; ++q2) {
      float4 mv = mr[q2];
      y += mv.x * wv[q2 * 4] + mv.y * wv[q2 * 4 + 1] + mv.z * wv[q2 * 4 + 2] + mv.w * wv[q2 * 4 + 3];
    }
    float pr = y * wv[t];
    pr += __shfl_xor(pr, 1); pr += __shfl_xor(pr, 2); pr += __shfl_xor(pr, 4);
    pr += __shfl_xor(pr, 8); pr += __shfl_xor(pr, 16); pr += __shfl_xor(pr, 32);
    if ((t & 63) == 0) red[t >> 6] = pr;
    __syncthreads();
    if (t == 0) qf4[sel * 128 + c] = red[0] + red[1];
    __syncthreads();
  }
}

// ---------------- K3p: finalize bn params ----------------
__global__ void k3p_params(const float* __restrict__ ssum,
                           const float* __restrict__ qf4,
                           const float* __restrict__ g1, const float* __restrict__ be1,
                           const float* __restrict__ ge, const float* __restrict__ bee,
                           const float* __restrict__ g3, const float* __restrict__ be3,
                           float* __restrict__ params) {
  int c = threadIdx.x;
  if (c >= 128) return;
  const float cnt1 = 1.f / 96000.f;
  {
    float m = ssum[SS_BN1S + c] * cnt1;
    float var = (ssum[SS_BN1S2 + c] + qf4[c]) * cnt1 - m * m;
    float s = g1[c] * rsqrtf(fmaxf(var, 0.f) + EPSV);
    params[c] = s; params[128 + c] = be1[c] - m * s;
  }
  {
    float m = ssum[SS_BNES + c] * cnt1;
    float var = (ssum[SS_BNES2 + c] + qf4[128 + c]) * cnt1 - m * m;
    float s = ge[c] * rsqrtf(fmaxf(var, 0.f) + EPSV);
    params[256 + c] = s; params[384 + c] = bee[c] - m * s;
  }
  {
    float Nf = (float)NATOMS;
    float A_ = ssum[SS_A + c], A2 = ssum[SS_A2 + c];
    float U2 = qf4[256 + c], V2 = qf4[384 + c];
    float Ub = ssum[SS_UB + c], Vb = ssum[SS_VB + c];
    float AU = ssum[SS_AU + c], AV = ssum[SS_AV + c], UV = ssum[SS_UV + c];
    float m = (A_ + Ub + Vb) / Nf;
    float ez2 = A2 / Nf + (U2 + V2) / (Nf * 12.f) + 2.f * (AU + AV + UV) / Nf;
    float var = ez2 - m * m;
    float s = g3[c] * rsqrtf(fmaxf(var, 0.f) + EPSV);
    params[512 + c] = s; params[640 + c] = be3[c] - m * s;
  }
}

// ---------------- K4: main pass (verbatim from R11) ----------------
__global__ __launch_bounds__(256, 4) void k4_main(const float* __restrict__ atom_in,
                                                  const float* __restrict__ nbr_fea,
                                                  const int* __restrict__ nidx,
                                                  const float* __restrict__ WaT,
                                                  const float* __restrict__ b_full,
                                                  const float* __restrict__ b_edge,
                                                  const float* __restrict__ b_3body,
                                                  const u16* __restrict__ XB,
                                                  const u16* __restrict__ WTA,
                                                  const u16* __restrict__ WTE,
                                                  const float* __restrict__ params,
                                                  float* __restrict__ tbuf,
                                                  float* __restrict__ out_nbr,
                                                  float* __restrict__ bn2scr) {
  __shared__ __align__(16) char smem[36224];
  char* nbrT      = smem;
  char* xjT       = smem + 6144;
  u16* u_s        = (u16*)(smem + 14336);
  float* ownv     = (float*)(smem + 27008);
  float* t2buf    = (float*)(smem + 29056);
  float* params_s = (float*)(smem + 30080);
  float* p3_s     = (float*)(smem + 32128);
  float* a_s      = (float*)(smem + 33152);
  float* xown     = (float*)(smem + 35200);
  u16* v_s        = (u16*)smem;
  float* redscr2  = (float*)(smem + 14336);
  int t = threadIdx.x, l = t & 63, w = t >> 6;
  int ab = blockIdx.x * AB, eb = ab * 12;

  for (int u = t; u < ROWS * 4; u += 256) {
    int row = u >> 2, c16 = (u & 3) * 16;
    stage_row16((short*)nbrT, row, c16, nbr_fea + (size_t)(eb + row) * 64 + c16);
  }
  stage_xj(XB, nidx, eb, ab, xjT, t);
  xown[t] = atom_in[(size_t)ab * 64 + t];
  params_s[t] = params[t];
  params_s[t + 256] = params[t + 256];
  p3_s[t] = params[512 + t];
  t2buf[t] = 0.f;
  __syncthreads();

  {
    int c = t & 127, h = t >> 7;
    float dv0, dv1;
    aterm_dot(WaT, xown, c, h, dv0, dv1);
    float s3 = p3_s[c], t3 = p3_s[128 + c];
    float b3v = b_3body[c];
    a_s[(2 * h) * 128 + c] = (dv0 + b3v) * s3 + t3;
    a_s[(2 * h + 1) * 128 + c] = (dv1 + b3v) * s3 + t3;
  }

#pragma unroll
  for (int b = 0; b < 2; ++b) {
    f32x4 acc[3][2];
    mfma_dual<3>(xjT, nbrT, WTA, WTE, b ? 384 : 128, b * 128, w, l, acc);
    mfma_own(xjT, WTA, b ? 256 : 0, w, l, ownv);
    int col0 = (w << 4) + (l & 15), col1 = col0 + 64;
    int g = l >> 4;
    const float* bp = b ? b_edge : b_full;
    float bias0 = bp[col0], bias1 = bp[col1];
    float sc0 = params_s[b * 256 + col0], sh0 = params_s[b * 256 + 128 + col0];
    float sc1 = params_s[b * 256 + col1], sh1 = params_s[b * 256 + 128 + col1];
#pragma unroll
    for (int rt = 0; rt < 3; ++rt) {
      int a12 = (rt * 16 + g * 4) / 12;
      float o0 = ownv[a12 * 128 + col0] + bias0;
      float o1 = ownv[a12 * 128 + col1] + bias1;
      float gsum = 0.f;
#pragma unroll
      for (int r = 0; r < 4; ++r) {
        int row = rt * 16 + g * 4 + r;
        float v0 = acc[rt][0][r] + o0;
        float v1 = acc[rt][1][r] + o1;
        float gate = sigf(v0 * sc0 + sh0) * spf(v1 * sc1 + sh1);
        if (b == 0) {
          gsum += gate;
        } else {
          size_t eg = (size_t)(eb + row) * 64 + col0;
          out_nbr[eg] = nbr_fea[eg] + gate;
        }
      }
      if (b == 0) atomicAdd(&t2buf[a12 * 64 + col0], gsum);
    }
  }

  {
    f32x4 acc[3][2];
    mfma_dual<3>(xjT, nbrT, WTA, WTE, 512, 256, w, l, acc);
    int col0 = (w << 4) + (l & 15), col1 = col0 + 64;
    int g = l >> 4;
    float s30 = p3_s[col0], s31 = p3_s[col1];
#pragma unroll
    for (int rt = 0; rt < 3; ++rt) {
#pragma unroll
      for (int r = 0; r < 4; ++r) {
        int row = rt * 16 + g * 4 + r;
        u_s[stg_idx(row, col0)] = f2bf(acc[rt][0][r] * s30);
        u_s[stg_idx(row, col1)] = f2bf(acc[rt][1][r] * s31);
      }
    }
  }
  {
    f32x4 acc[3][2];
    mfma_dual<3>(xjT, nbrT, WTA, WTE, 640, 384, w, l, acc);
    __syncthreads();
    int col0 = (w << 4) + (l & 15), col1 = col0 + 64;
    int g = l >> 4;
    float s30 = p3_s[col0], s31 = p3_s[col1];
#pragma unroll
    for (int rt = 0; rt < 3; ++rt) {
#pragma unroll
      for (int r = 0; r < 4; ++r) {
        int row = rt * 16 + g * 4 + r;
        v_s[stg_idx(row, col0)] = f2bf(acc[rt][0][r] * s30);
        v_s[stg_idx(row, col1)] = f2bf(acc[rt][1][r] * s31);
      }
    }
  }
  __syncthreads();

  float acc3 = 0.f;
  {
    int c = l, a = w;
    float af = a_s[a * 128 + c], ac = a_s[a * 128 + 64 + c];
    float Fl[12], Hl[12];
#pragma unroll
    for (int j2 = 0; j2 < 12; ++j2) {
      float vf = bf2f(v_s[stg_idx(a * 12 + j2, c)]);
      float vc = bf2f(v_s[stg_idx(a * 12 + j2, 64 + c)]);
      Fl[j2] = __expf(-vf);
      Hl[j2] = __expf(vc);
    }
    for (int j = 0; j < 12; ++j) {
      float uf = bf2f(u_s[stg_idx(a * 12 + j, c)]);
      float uc = bf2f(u_s[stg_idx(a * 12 + j, 64 + c)]);
      float Ej = __expf(-(af + uf));
      float Gj = __expf(ac + uc);
#pragma unroll
      for (int l2 = 0; l2 < 12; ++l2) {
        float p = fmaf(Ej, Fl[l2], 1.f);
        float q = fmaf(Gj, Hl[l2], 1.f);
        acc3 += __builtin_amdgcn_rcpf(p) * __log2f(q);
      }
    }
  }
  __syncthreads();

  {
    float x = t2buf[t] + acc3 * 0.6931471805599453f;
    tbuf[(size_t)(ab + w) * 64 + l] = x;
    redscr2[t] = x;
    redscr2[256 + t] = x * x;
    __syncthreads();
    if (t < 64) {
      float s = redscr2[t] + redscr2[t + 64] + redscr2[t + 128] + redscr2[t + 192];
      float s2 = redscr2[256 + t] + redscr2[256 + t + 64] + redscr2[256 + t + 128] + redscr2[256 + t + 192];
      bn2scr[(size_t)t * 2048 + blockIdx.x] = s;
      bn2scr[(size_t)(64 + t) * 2048 + blockIdx.x] = s2;
    }
  }
}

// ---------------- K5: reduce bn2 partials -> bn2sum[128] ----------------
__global__ __launch_bounds__(256) void k5_reduce(const float* __restrict__ bn2scr,
                                                 float* __restrict__ bn2sum) {
  __shared__ float wsum[4];
  int c = blockIdx.x, t = threadIdx.x;
  float s = 0.f;
#pragma unroll 4
  for (int i = t; i < NBLK; i += 256) s += bn2scr[(size_t)c * 2048 + i];
  s += __shfl_xor(s, 1); s += __shfl_xor(s, 2); s += __shfl_xor(s, 4);
  s += __shfl_xor(s, 8); s += __shfl_xor(s, 16); s += __shfl_xor(s, 32);
  if ((t & 63) == 0) wsum[t >> 6] = s;
  __syncthreads();
  if (t == 0) bn2sum[c] = wsum[0] + wsum[1] + wsum[2] + wsum[3];
}

// ---------------- K6: bn2 + final softplus ----------------
__global__ __launch_bounds__(256) void k6_out(const float* __restrict__ atom_in,
                                              const float* __restrict__ tbuf,
                                              const float* __restrict__ bn2sum,
                                              const float* __restrict__ g2,
                                              const float* __restrict__ be2,
                                              float* __restrict__ out_atom) {
  __shared__ float sc[64], sh[64];
  int t = threadIdx.x;
  if (t < 64) {
    float S = bn2sum[t], S2 = bn2sum[64 + t];
    float m = S * (1.f / (float)NATOMS);
    float var = S2 * (1.f / (float)NATOMS) - m * m;
    float s = g2[t] * rsqrtf(fmaxf(var, 0.f) + EPSV);
    sc[t] = s; sh[t] = be2[t] - m * s;
  }
  __syncthreads();
  int i = blockIdx.x * 256 + t;
  if (i < NATOMS * 64) {
    int c = i & 63;
    float v = atom_in[i] + tbuf[i] * sc[c] + sh[c];
    out_atom[i] = spf(v);
  }
}

extern "C" void kernel_launch(void* const* d_in, const int* in_sizes, int n_in,
                              void* d_out, int out_size, void* d_ws, size_t ws_size,
                              hipStream_t stream) {
  if (ws_size < (size_t)WS_NEED) return;
  const float* atom_in = (const float*)d_in[0];
  const float* nbr_fea = (const float*)d_in[1];
  const int* nidx = (const int*)d_in[2];
  const float* W_full = (const float*)d_in[3];
  const float* b_full = (const float*)d_in[4];
  const float* g1 = (const float*)d_in[5];
  const float* be1 = (const float*)d_in[6];
  const float* W_edge = (const float*)d_in[7];
  const float* b_edge = (const float*)d_in[8];
  const float* ge = (const float*)d_in[9];
  const float* bee = (const float*)d_in[10];
  const float* W_3body = (const float*)d_in[11];
  const float* b_3body = (const float*)d_in[12];
  const float* g3 = (const float*)d_in[13];
  const float* be3 = (const float*)d_in[14];
  const float* g2 = (const float*)d_in[15];
  const float* be2 = (const float*)d_in[16];

  char* ws = (char*)d_ws;
  u16* XB = (u16*)(ws + XB_OFF);
  u16* WTA = (u16*)(ws + WTA_OFF);
  u16* WTE = (u16*)(ws + WTE_OFF);
  float* WaT = (float*)(ws + WAT_OFF);
  float* Mrep = (float*)(ws + MREP_OFF);
  float* Mfin = (float*)(ws + MFIN_OFF);
  float* qf4 = (float*)(ws + QF4_OFF);
  float* ssum = (float*)(ws + SSUM_OFF);
  float* bn2sum = ssum + KREC;
  float* params = (float*)(ws + PARAMS_OFF);
  float* tbuf = (float*)(ws + TBUF_OFF);

  float* out_atom = (float*)d_out;
  float* out_nbr = out_atom + NATOMS * 64;
  float* krec = out_nbr;     // scratch until k4 overwrites (500*1408*4 = 2.8 MB)
  float* bn2scr = out_atom;  // scratch until k6 overwrites

  k0_prep<<<2000, 256, 0, stream>>>(atom_in, W_full, W_edge, W_3body, XB, WTA, WTE, WaT,
                                    Mrep, ssum);
  kzg_stats<<<NZG, 256, 0, stream>>>(nbr_fea, nidx, b_full, b_edge, b_3body,
                                     XB, WTA, WTE, Mrep, krec);
  k3r_reduce<<<84, 256, 0, stream>>>(krec, Mrep, ssum, Mfin);
  k3q_qf<<<128, 128, 0, stream>>>(Mfin, W_full, W_edge, W_3body, qf4);
  k3p_params<<<1, 128, 0, stream>>>(ssum, qf4, g1, be1, ge, bee, g3, be3, params);
  k4_main<<<NBLK, 256, 0, stream>>>(atom_in, nbr_fea, nidx, WaT, b_full, b_edge, b_3body,
                                    XB, WTA, WTE, params, tbuf, out_nbr, bn2scr);
  k5_reduce<<<128, 256, 0, stream>>>(bn2scr, bn2sum);
  k6_out<<<2000, 256, 0, stream>>>(atom_in, tbuf, bn2sum, g2, be2, out_atom);
}